// Round 1
// baseline (1247.717 us; speedup 1.0000x reference)
//
#include <hip/hip_runtime.h>
#include <math.h>

#define S_DIM 512
#define R_DIM 384
#define CM 64
#define CZ 128
#define NH 8
#define CH 32
#define HC 256

// ---------------------------------------------------------------------------
// Kernel A: bias = LN(z) @ w_b + INF*(z_mask-1); w = softmax_j(bias)
// one block per i-row; writes w_soft as [H][R][R] (row i, contiguous j)
// ---------------------------------------------------------------------------
__global__ __launch_bounds__(256) void kA_bias_softmax(
    const float* __restrict__ z, const float* __restrict__ z_mask,
    const float* __restrict__ ln_z_g, const float* __restrict__ ln_z_b,
    const float* __restrict__ w_b, float* __restrict__ w_soft)
{
    __shared__ float bias_lds[R_DIM * NH];   // 12 KB
    __shared__ float znorm[4][CZ];           // 2 KB
    const int i    = blockIdx.x;
    const int tid  = threadIdx.x;
    const int wv   = tid >> 6;
    const int lane = tid & 63;

    for (int jj = 0; jj < R_DIM / 4; ++jj) {
        const int j = jj * 4 + wv;
        const float2 zz = *reinterpret_cast<const float2*>(
            z + ((size_t)(i * R_DIM + j)) * CZ + lane * 2);
        float s1 = zz.x + zz.y;
        float s2 = zz.x * zz.x + zz.y * zz.y;
        #pragma unroll
        for (int msk = 32; msk >= 1; msk >>= 1) {
            s1 += __shfl_xor(s1, msk);
            s2 += __shfl_xor(s2, msk);
        }
        const float mu   = s1 * (1.0f / CZ);
        const float var  = s2 * (1.0f / CZ) - mu * mu;
        const float rstd = rsqrtf(var + 1e-5f);
        const int c0 = lane * 2;
        znorm[wv][c0]     = (zz.x - mu) * rstd * ln_z_g[c0]     + ln_z_b[c0];
        znorm[wv][c0 + 1] = (zz.y - mu) * rstd * ln_z_g[c0 + 1] + ln_z_b[c0 + 1];
        __syncthreads();
        const int h = lane & 7, seg = lane >> 3;
        float acc = 0.f;
        #pragma unroll
        for (int t = 0; t < 16; ++t) {
            const int c = seg * 16 + t;
            acc += znorm[wv][c] * w_b[c * NH + h];
        }
        acc += __shfl_xor(acc, 8);
        acc += __shfl_xor(acc, 16);
        acc += __shfl_xor(acc, 32);
        if (seg == 0)
            bias_lds[j * NH + h] = acc + 1e8f * (z_mask[(size_t)i * R_DIM + j] - 1.0f);
        __syncthreads();
    }

    // softmax over j per head
    for (int h = wv; h < NH; h += 4) {
        float vals[6];
        float mx = -1e30f;
        #pragma unroll
        for (int u = 0; u < 6; ++u) {
            vals[u] = bias_lds[(lane + u * 64) * NH + h];
            mx = fmaxf(mx, vals[u]);
        }
        #pragma unroll
        for (int msk = 32; msk >= 1; msk >>= 1) mx = fmaxf(mx, __shfl_xor(mx, msk));
        float sum = 0.f;
        #pragma unroll
        for (int u = 0; u < 6; ++u) { vals[u] = __expf(vals[u] - mx); sum += vals[u]; }
        #pragma unroll
        for (int msk = 32; msk >= 1; msk >>= 1) sum += __shfl_xor(sum, msk);
        const float inv = 1.0f / sum;
        #pragma unroll
        for (int u = 0; u < 6; ++u)
            w_soft[((size_t)h * R_DIM + i) * R_DIM + lane + u * 64] = vals[u] * inv;
    }
}

// ---------------------------------------------------------------------------
// Kernel B: per (s,j): mln = LN(m); V = (mln@w_v)*mask -> [H][j][sc][32];
//           G = sigmoid(mln@w_g) -> [si][256].  GEMM-shaped, LN fused in
//           A-tile load. Grid: (8 n-tiles, SCH*3 row-panels of 128).
// ---------------------------------------------------------------------------
__global__ __launch_bounds__(256) void kB_proj(
    const float* __restrict__ m_chunk,     // m + s0*R*64
    const float* __restrict__ mask_chunk,  // msa_mask + s0*R
    const float* __restrict__ ln_g, const float* __restrict__ ln_b,
    const float* __restrict__ w_v, const float* __restrict__ w_g,
    float* __restrict__ Vbuf, float* __restrict__ gbuf, int SCH)
{
    __shared__ float A[128 * 65];
    __shared__ float Bt[64 * 64];
    const int tid = threadIdx.x;
    const int yb  = blockIdx.x;           // 0..7 : 0-3 -> w_v, 4-7 -> w_g
    const int si0 = blockIdx.y * 128;

    { // stage raw m rows
        const int r = tid >> 1, half = tid & 1;
        const float* src = m_chunk + (size_t)(si0 + r) * CM + half * 32;
        float* dst = &A[r * 65 + half * 32];
        #pragma unroll
        for (int e = 0; e < 8; ++e) {
            float4 v4 = *reinterpret_cast<const float4*>(src + e * 4);
            dst[e * 4 + 0] = v4.x; dst[e * 4 + 1] = v4.y;
            dst[e * 4 + 2] = v4.z; dst[e * 4 + 3] = v4.w;
        }
    }
    __syncthreads();
    { // layernorm each row in place
        const int wv = tid >> 6, lane = tid & 63;
        for (int u = 0; u < 32; ++u) {
            const int r = wv * 32 + u;
            float v = A[r * 65 + lane];
            float s1 = v, s2 = v * v;
            #pragma unroll
            for (int msk = 32; msk >= 1; msk >>= 1) {
                s1 += __shfl_xor(s1, msk);
                s2 += __shfl_xor(s2, msk);
            }
            const float mu   = s1 * (1.f / 64);
            const float var  = s2 * (1.f / 64) - mu * mu;
            const float rstd = rsqrtf(var + 1e-5f);
            A[r * 65 + lane] = (v - mu) * rstd * ln_g[lane] + ln_b[lane];
        }
    }
    { // stage weight tile
        const float* W = (yb < 4) ? (w_v + yb * 64) : (w_g + (yb - 4) * 64);
        const int kk = tid >> 2, q = tid & 3;
        #pragma unroll
        for (int e = 0; e < 4; ++e) {
            float4 v4 = *reinterpret_cast<const float4*>(W + (size_t)kk * HC + q * 16 + e * 4);
            *reinterpret_cast<float4*>(&Bt[kk * 64 + q * 16 + e * 4]) = v4;
        }
    }
    __syncthreads();

    const int tx = tid & 15, ty = tid >> 4;
    float acc[8][4] = {};
    #pragma unroll 4
    for (int kk = 0; kk < 64; ++kk) {
        float4 b = *reinterpret_cast<float4*>(&Bt[kk * 64 + tx * 4]);
        #pragma unroll
        for (int e = 0; e < 8; ++e) {
            float a = A[(ty * 8 + e) * 65 + kk];
            acc[e][0] += a * b.x; acc[e][1] += a * b.y;
            acc[e][2] += a * b.z; acc[e][3] += a * b.w;
        }
    }

    if (yb < 4) {
        #pragma unroll
        for (int e = 0; e < 8; ++e) {
            const int si = si0 + ty * 8 + e;
            const int sc = si / R_DIM, j = si % R_DIM;
            const float msk = mask_chunk[(size_t)sc * R_DIM + j];
            const int k = yb * 64 + tx * 4;
            const int h = k >> 5, c = k & 31;
            float4 o;
            o.x = acc[e][0] * msk; o.y = acc[e][1] * msk;
            o.z = acc[e][2] * msk; o.w = acc[e][3] * msk;
            *reinterpret_cast<float4*>(
                &Vbuf[(((size_t)h * R_DIM + j) * SCH + sc) * 32 + c]) = o;
        }
    } else {
        #pragma unroll
        for (int e = 0; e < 8; ++e) {
            const int si = si0 + ty * 8 + e;
            const int k = (yb - 4) * 64 + tx * 4;
            float4 o;
            o.x = 1.f / (1.f + __expf(-acc[e][0]));
            o.y = 1.f / (1.f + __expf(-acc[e][1]));
            o.z = 1.f / (1.f + __expf(-acc[e][2]));
            o.w = 1.f / (1.f + __expf(-acc[e][3]));
            *reinterpret_cast<float4*>(&gbuf[(size_t)si * HC + k]) = o;
        }
    }
}

// ---------------------------------------------------------------------------
// Kernel C: per-head GEMM o_pre[i, n] = sum_j W_h[i,j] * V_h[j,n]
// BM=128, BN=64, BK=16. Writes o_pre as [sc*R + i][h*32+c].
// ---------------------------------------------------------------------------
__global__ __launch_bounds__(256) void kC_einsum(
    const float* __restrict__ w_soft, const float* __restrict__ Vbuf,
    float* __restrict__ o_pre, int SCH)
{
    __shared__ float Wt[16 * 129];
    __shared__ float Vt[16 * 64];
    const int n0  = blockIdx.x * 64;
    const int i0  = blockIdx.y * 128;
    const int h   = blockIdx.z;
    const int tid = threadIdx.x;
    const int tx  = tid & 15, ty = tid >> 4;
    const int N   = SCH * 32;
    const float* Wp = w_soft + (size_t)h * R_DIM * R_DIM;
    const float* Vp = Vbuf + (size_t)h * R_DIM * N;
    float acc[8][4] = {};

    for (int k0 = 0; k0 < R_DIM; k0 += 16) {
        { // W tile transposed [k][i], pad 129
            const int r = tid >> 1, kh = tid & 1;
            const float* src = Wp + (size_t)(i0 + r) * R_DIM + k0 + kh * 8;
            #pragma unroll
            for (int e = 0; e < 2; ++e) {
                float4 v4 = *reinterpret_cast<const float4*>(src + e * 4);
                const int kl = kh * 8 + e * 4;
                Wt[(kl + 0) * 129 + r] = v4.x;
                Wt[(kl + 1) * 129 + r] = v4.y;
                Wt[(kl + 2) * 129 + r] = v4.z;
                Wt[(kl + 3) * 129 + r] = v4.w;
            }
        }
        { // V tile natural [k][n]
            const int kk = tid >> 4, n4 = (tid & 15) * 4;
            float4 v4 = *reinterpret_cast<const float4*>(
                Vp + (size_t)(k0 + kk) * N + n0 + n4);
            *reinterpret_cast<float4*>(&Vt[kk * 64 + n4]) = v4;
        }
        __syncthreads();
        #pragma unroll
        for (int kk = 0; kk < 16; ++kk) {
            float4 b = *reinterpret_cast<float4*>(&Vt[kk * 64 + tx * 4]);
            #pragma unroll
            for (int e = 0; e < 8; ++e) {
                float a = Wt[kk * 129 + ty * 8 + e];
                acc[e][0] += a * b.x; acc[e][1] += a * b.y;
                acc[e][2] += a * b.z; acc[e][3] += a * b.w;
            }
        }
        __syncthreads();
    }

    const int n  = n0 + tx * 4;
    const int sc = n >> 5, c = n & 31;
    #pragma unroll
    for (int e = 0; e < 8; ++e) {
        const int i = i0 + ty * 8 + e;
        *reinterpret_cast<float4*>(
            &o_pre[((size_t)sc * R_DIM + i) * HC + h * 32 + c]) =
            make_float4(acc[e][0], acc[e][1], acc[e][2], acc[e][3]);
    }
}

// ---------------------------------------------------------------------------
// Kernel D: out[si, :] = (g[si,:] * o_pre[si,:]) @ w_o   (K=256, N=64)
// ---------------------------------------------------------------------------
__global__ __launch_bounds__(256) void kD_out(
    const float* __restrict__ gbuf, const float* __restrict__ o_pre,
    const float* __restrict__ w_o, float* __restrict__ out_chunk, int SCH)
{
    __shared__ float A[128 * 65];
    __shared__ float Bt[64 * 64];
    const int si0 = blockIdx.x * 128;
    const int tid = threadIdx.x;
    const int tx  = tid & 15, ty = tid >> 4;
    float acc[8][4] = {};

    for (int k0 = 0; k0 < HC; k0 += 64) {
        { // A tile = g * o_pre
            const int r = tid >> 1, half = tid & 1;
            const size_t base = (size_t)(si0 + r) * HC + k0 + half * 32;
            float* dst = &A[r * 65 + half * 32];
            #pragma unroll
            for (int e = 0; e < 8; ++e) {
                float4 gg = *reinterpret_cast<const float4*>(gbuf + base + e * 4);
                float4 oo = *reinterpret_cast<const float4*>(o_pre + base + e * 4);
                dst[e * 4 + 0] = gg.x * oo.x; dst[e * 4 + 1] = gg.y * oo.y;
                dst[e * 4 + 2] = gg.z * oo.z; dst[e * 4 + 3] = gg.w * oo.w;
            }
        }
        { // w_o tile
            const int kk = tid >> 2, q = tid & 3;
            #pragma unroll
            for (int e = 0; e < 4; ++e) {
                float4 v4 = *reinterpret_cast<const float4*>(
                    w_o + (size_t)(k0 + kk) * CM + q * 16 + e * 4);
                *reinterpret_cast<float4*>(&Bt[kk * 64 + q * 16 + e * 4]) = v4;
            }
        }
        __syncthreads();
        #pragma unroll 8
        for (int kk = 0; kk < 64; ++kk) {
            float4 b = *reinterpret_cast<float4*>(&Bt[kk * 64 + tx * 4]);
            #pragma unroll
            for (int e = 0; e < 8; ++e) {
                float a = A[(ty * 8 + e) * 65 + kk];
                acc[e][0] += a * b.x; acc[e][1] += a * b.y;
                acc[e][2] += a * b.z; acc[e][3] += a * b.w;
            }
        }
        __syncthreads();
    }
    #pragma unroll
    for (int e = 0; e < 8; ++e) {
        *reinterpret_cast<float4*>(
            &out_chunk[(size_t)(si0 + ty * 8 + e) * CM + tx * 4]) =
            make_float4(acc[e][0], acc[e][1], acc[e][2], acc[e][3]);
    }
}

// ---------------------------------------------------------------------------
extern "C" void kernel_launch(void* const* d_in, const int* in_sizes, int n_in,
                              void* d_out, int out_size, void* d_ws, size_t ws_size,
                              hipStream_t stream)
{
    const float* m        = (const float*)d_in[0];
    const float* z        = (const float*)d_in[1];
    const float* msa_mask = (const float*)d_in[2];
    const float* z_mask   = (const float*)d_in[3];
    const float* ln_m_g   = (const float*)d_in[4];
    const float* ln_m_b   = (const float*)d_in[5];
    const float* w_v      = (const float*)d_in[6];
    const float* w_g      = (const float*)d_in[7];
    const float* ln_z_g   = (const float*)d_in[8];
    const float* ln_z_b   = (const float*)d_in[9];
    const float* w_b      = (const float*)d_in[10];
    const float* w_o      = (const float*)d_in[11];
    float* out = (float*)d_out;

    const size_t wsoft_bytes = (size_t)NH * R_DIM * R_DIM * 4;
    int SCH = 256;  // cap: keeps chunk buffers L3-resident
    while (SCH > 2 && wsoft_bytes + 3ull * SCH * R_DIM * HC * 4 > ws_size) SCH >>= 1;

    char* p = (char*)d_ws;
    float* w_soft = (float*)p; p += wsoft_bytes;
    const size_t cb = (size_t)SCH * R_DIM * HC * 4;
    float* Vbuf = (float*)p; p += cb;
    float* gbuf = (float*)p; p += cb;
    float* obuf = (float*)p;

    kA_bias_softmax<<<R_DIM, 256, 0, stream>>>(z, z_mask, ln_z_g, ln_z_b, w_b, w_soft);

    for (int s0 = 0; s0 < S_DIM; s0 += SCH) {
        kB_proj<<<dim3(8, SCH * 3), 256, 0, stream>>>(
            m + (size_t)s0 * R_DIM * CM, msa_mask + (size_t)s0 * R_DIM,
            ln_m_g, ln_m_b, w_v, w_g, Vbuf, gbuf, SCH);
        kC_einsum<<<dim3(SCH / 2, 3, NH), 256, 0, stream>>>(w_soft, Vbuf, obuf, SCH);
        kD_out<<<dim3(SCH * 3), 256, 0, stream>>>(gbuf, obuf, w_o,
                                                  out + (size_t)s0 * R_DIM * CM, SCH);
    }
}

// Round 3
// 737.111 us; speedup vs baseline: 1.6927x; 1.6927x over previous
//
#include <hip/hip_runtime.h>
#include <math.h>

#define S_DIM 512
#define R_DIM 384
#define CM 64
#define CZ 128
#define NH 8
#define CH 32
#define HC 256

typedef unsigned short u16;
typedef __attribute__((ext_vector_type(8))) __bf16 bf16x8;
typedef __attribute__((ext_vector_type(4))) float f32x4;

static __device__ __forceinline__ u16 f2bf(float f) {
    unsigned int u = __float_as_uint(f);
    unsigned int r = (u + 0x7fffu + ((u >> 16) & 1u)) >> 16;
    return (u16)r;
}

// ---------------------------------------------------------------------------
// Kernel A: bias = LN(z) @ w_b + INF*(z_mask-1); w = softmax_j(bias)
// one block per i-row; writes w_soft as bf16 [H][R][R] (row i, contiguous j)
// ---------------------------------------------------------------------------
__global__ __launch_bounds__(256) void kA_bias_softmax(
    const float* __restrict__ z, const float* __restrict__ z_mask,
    const float* __restrict__ ln_z_g, const float* __restrict__ ln_z_b,
    const float* __restrict__ w_b, u16* __restrict__ w_soft)
{
    __shared__ float bias_lds[R_DIM * NH];   // 12 KB
    __shared__ float znorm[4][CZ];           // 2 KB
    const int i    = blockIdx.x;
    const int tid  = threadIdx.x;
    const int wv   = tid >> 6;
    const int lane = tid & 63;

    for (int jj = 0; jj < R_DIM / 4; ++jj) {
        const int j = jj * 4 + wv;
        const float2 zz = *reinterpret_cast<const float2*>(
            z + ((size_t)(i * R_DIM + j)) * CZ + lane * 2);
        float s1 = zz.x + zz.y;
        float s2 = zz.x * zz.x + zz.y * zz.y;
        #pragma unroll
        for (int msk = 32; msk >= 1; msk >>= 1) {
            s1 += __shfl_xor(s1, msk);
            s2 += __shfl_xor(s2, msk);
        }
        const float mu   = s1 * (1.0f / CZ);
        const float var  = s2 * (1.0f / CZ) - mu * mu;
        const float rstd = rsqrtf(var + 1e-5f);
        const int c0 = lane * 2;
        znorm[wv][c0]     = (zz.x - mu) * rstd * ln_z_g[c0]     + ln_z_b[c0];
        znorm[wv][c0 + 1] = (zz.y - mu) * rstd * ln_z_g[c0 + 1] + ln_z_b[c0 + 1];
        __syncthreads();
        const int h = lane & 7, seg = lane >> 3;
        float acc = 0.f;
        #pragma unroll
        for (int t = 0; t < 16; ++t) {
            const int c = seg * 16 + t;
            acc += znorm[wv][c] * w_b[c * NH + h];
        }
        acc += __shfl_xor(acc, 8);
        acc += __shfl_xor(acc, 16);
        acc += __shfl_xor(acc, 32);
        if (seg == 0)
            bias_lds[j * NH + h] = acc + 1e8f * (z_mask[(size_t)i * R_DIM + j] - 1.0f);
        __syncthreads();
    }

    // softmax over j per head
    for (int h = wv; h < NH; h += 4) {
        float vals[6];
        float mx = -1e30f;
        #pragma unroll
        for (int u = 0; u < 6; ++u) {
            vals[u] = bias_lds[(lane + u * 64) * NH + h];
            mx = fmaxf(mx, vals[u]);
        }
        #pragma unroll
        for (int msk = 32; msk >= 1; msk >>= 1) mx = fmaxf(mx, __shfl_xor(mx, msk));
        float sum = 0.f;
        #pragma unroll
        for (int u = 0; u < 6; ++u) { vals[u] = __expf(vals[u] - mx); sum += vals[u]; }
        #pragma unroll
        for (int msk = 32; msk >= 1; msk >>= 1) sum += __shfl_xor(sum, msk);
        const float inv = 1.0f / sum;
        #pragma unroll
        for (int u = 0; u < 6; ++u)
            w_soft[((size_t)h * R_DIM + i) * R_DIM + lane + u * 64] =
                f2bf(vals[u] * inv);
    }
}

// ---------------------------------------------------------------------------
// Kernel B: per (s,j): mln = LN(m); V = (mln@w_v)*mask -> bf16 Vt[H][n][j];
//           G = sigmoid(mln@w_g) -> f32 [si][256].
// Grid: (8 n-tiles, SCH*3 row-panels of 128). Each block covers one sc.
// ---------------------------------------------------------------------------
__global__ __launch_bounds__(256) void kB_proj(
    const float* __restrict__ m_chunk,     // m + s0*R*64
    const float* __restrict__ mask_chunk,  // msa_mask + s0*R  (flat si index)
    const float* __restrict__ ln_g, const float* __restrict__ ln_b,
    const float* __restrict__ w_v, const float* __restrict__ w_g,
    u16* __restrict__ Vt, float* __restrict__ gbuf, int SCH)
{
    __shared__ float A[128 * 65];
    __shared__ float Bt[64 * 64];
    const int tid = threadIdx.x;
    const int yb  = blockIdx.x;           // 0..3 -> w_v, 4..7 -> w_g
    const int si0 = blockIdx.y * 128;

    { // stage raw m rows
        const int r = tid >> 1, half = tid & 1;
        const float* src = m_chunk + (size_t)(si0 + r) * CM + half * 32;
        float* dst = &A[r * 65 + half * 32];
        #pragma unroll
        for (int e = 0; e < 8; ++e) {
            float4 v4 = *reinterpret_cast<const float4*>(src + e * 4);
            dst[e * 4 + 0] = v4.x; dst[e * 4 + 1] = v4.y;
            dst[e * 4 + 2] = v4.z; dst[e * 4 + 3] = v4.w;
        }
    }
    __syncthreads();
    { // layernorm each row in place
        const int wv = tid >> 6, lane = tid & 63;
        for (int u = 0; u < 32; ++u) {
            const int r = wv * 32 + u;
            float v = A[r * 65 + lane];
            float s1 = v, s2 = v * v;
            #pragma unroll
            for (int msk = 32; msk >= 1; msk >>= 1) {
                s1 += __shfl_xor(s1, msk);
                s2 += __shfl_xor(s2, msk);
            }
            const float mu   = s1 * (1.f / 64);
            const float var  = s2 * (1.f / 64) - mu * mu;
            const float rstd = rsqrtf(var + 1e-5f);
            A[r * 65 + lane] = (v - mu) * rstd * ln_g[lane] + ln_b[lane];
        }
    }
    { // stage weight tile
        const float* W = (yb < 4) ? (w_v + yb * 64) : (w_g + (yb - 4) * 64);
        const int kk = tid >> 2, q = tid & 3;
        #pragma unroll
        for (int e = 0; e < 4; ++e) {
            float4 v4 = *reinterpret_cast<const float4*>(W + (size_t)kk * HC + q * 16 + e * 4);
            *reinterpret_cast<float4*>(&Bt[kk * 64 + q * 16 + e * 4]) = v4;
        }
    }
    __syncthreads();

    const int tx = tid & 15, ty = tid >> 4;
    float acc[8][4] = {};
    #pragma unroll 4
    for (int kk = 0; kk < 64; ++kk) {
        float4 b = *reinterpret_cast<float4*>(&Bt[kk * 64 + tx * 4]);
        #pragma unroll
        for (int e = 0; e < 8; ++e) {
            float a = A[(ty * 8 + e) * 65 + kk];
            acc[e][0] += a * b.x; acc[e][1] += a * b.y;
            acc[e][2] += a * b.z; acc[e][3] += a * b.w;
        }
    }

    if (yb < 4) {
        // transpose through LDS -> bf16 Vt[h][n = sc*32+c][j], j contiguous
        __syncthreads();               // done reading A
        u16* T = (u16*)A;              // 64 x 128 bf16 = 16 KB
        #pragma unroll
        for (int e = 0; e < 8; ++e) {
            const int si = si0 + ty * 8 + e;
            const float msk = mask_chunk[si];   // mask[sc*R + j] == mask[si]
            #pragma unroll
            for (int q = 0; q < 4; ++q)
                T[(tx * 4 + q) * 128 + ty * 8 + e] = f2bf(acc[e][q] * msk);
        }
        __syncthreads();
        const int sc = si0 / R_DIM, j0 = si0 % R_DIM;
        const size_t Nn = (size_t)SCH * 32;
        #pragma unroll
        for (int rep = 0; rep < 4; ++rep) {
            const int c = rep * 256 + tid;      // 0..1023
            const int kk = c >> 4, ch = c & 15; // row, 16B chunk
            const int kg = yb * 64 + kk;
            const int h = kg >> 5, cc = kg & 31;
            u16* dst = Vt + ((size_t)h * Nn + sc * 32 + cc) * R_DIM + j0 + ch * 8;
            *reinterpret_cast<uint4*>(dst) =
                *reinterpret_cast<const uint4*>(&T[kk * 128 + ch * 8]);
        }
    } else {
        #pragma unroll
        for (int e = 0; e < 8; ++e) {
            const int si = si0 + ty * 8 + e;
            const int k = (yb - 4) * 64 + tx * 4;
            float4 o;
            o.x = 1.f / (1.f + __expf(-acc[e][0]));
            o.y = 1.f / (1.f + __expf(-acc[e][1]));
            o.z = 1.f / (1.f + __expf(-acc[e][2]));
            o.w = 1.f / (1.f + __expf(-acc[e][3]));
            *reinterpret_cast<float4*>(&gbuf[(size_t)si * HC + k]) = o;
        }
    }
}

// ---------------------------------------------------------------------------
// Kernel C: per-head MFMA GEMM  o_pre[i,n] = sum_j W_h[i,j] * V_h[j,n]
// A = w_soft bf16 [h][i][j] (K-major); B = Vt bf16 [h][n][j] (K-major).
// 128x128 block tile, BK=32, 4 waves x (64x64), mfma_f32_16x16x32_bf16.
// Writes o_pre f32 as [sc*R + i][h*32+c].
// ---------------------------------------------------------------------------
__global__ __launch_bounds__(256) void kC_mfma(
    const u16* __restrict__ Wsoft, const u16* __restrict__ Vt,
    float* __restrict__ o_pre, int SCH)
{
    constexpr int LDSP = 40;                 // padded row stride (bf16)
    __shared__ u16 lds_a[128 * LDSP];        // 10 KB
    __shared__ u16 lds_b[128 * LDSP];        // 10 KB
    const int N   = SCH * 32;
    const int n0  = blockIdx.x * 128;
    const int i0  = blockIdx.y * 128;
    const int h   = blockIdx.z;
    const int tid = threadIdx.x;
    const int lane = tid & 63;
    const int w    = tid >> 6;
    const int wr   = (w >> 1) * 64;
    const int wc   = (w & 1) * 64;

    const u16* Wp = Wsoft + (size_t)h * R_DIM * R_DIM;
    const u16* Vp = Vt    + (size_t)h * N * R_DIM;

    f32x4 acc[4][4] = {};

    for (int k0 = 0; k0 < R_DIM; k0 += 32) {
        __syncthreads();
        #pragma unroll
        for (int rep = 0; rep < 2; ++rep) {
            const int c = rep * 256 + tid;   // 0..511
            const int row = c >> 2, q = c & 3;
            uint4 va = *reinterpret_cast<const uint4*>(
                Wp + (size_t)(i0 + row) * R_DIM + k0 + q * 8);
            *reinterpret_cast<uint4*>(&lds_a[row * LDSP + q * 8]) = va;
            uint4 vb = *reinterpret_cast<const uint4*>(
                Vp + (size_t)(n0 + row) * R_DIM + k0 + q * 8);
            *reinterpret_cast<uint4*>(&lds_b[row * LDSP + q * 8]) = vb;
        }
        __syncthreads();

        bf16x8 afrag[4], bfrag[4];
        #pragma unroll
        for (int mm = 0; mm < 4; ++mm) {
            const int row = wr + mm * 16 + (lane & 15);
            afrag[mm] = *reinterpret_cast<const bf16x8*>(
                &lds_a[row * LDSP + (lane >> 4) * 8]);
        }
        #pragma unroll
        for (int nn = 0; nn < 4; ++nn) {
            const int row = wc + nn * 16 + (lane & 15);
            bfrag[nn] = *reinterpret_cast<const bf16x8*>(
                &lds_b[row * LDSP + (lane >> 4) * 8]);
        }
        #pragma unroll
        for (int mm = 0; mm < 4; ++mm)
            #pragma unroll
            for (int nn = 0; nn < 4; ++nn)
                acc[mm][nn] = __builtin_amdgcn_mfma_f32_16x16x32_bf16(
                    afrag[mm], bfrag[nn], acc[mm][nn], 0, 0, 0);
    }

    // epilogue: C/D layout col=lane&15, row=(lane>>4)*4+r
    const int r4 = (lane >> 4) * 4;
    const int cl = lane & 15;
    #pragma unroll
    for (int mm = 0; mm < 4; ++mm) {
        #pragma unroll
        for (int nn = 0; nn < 4; ++nn) {
            const int i = i0 + wr + mm * 16 + r4;
            const int n = n0 + wc + nn * 16 + cl;
            const int sc = n >> 5, cc = n & 31;
            float* dst = &o_pre[((size_t)sc * R_DIM + i) * HC + h * 32 + cc];
            #pragma unroll
            for (int r = 0; r < 4; ++r)
                dst[(size_t)r * HC] = acc[mm][nn][r];
        }
    }
}

// ---------------------------------------------------------------------------
// Kernel D: out[si, :] = (g[si,:] * o_pre[si,:]) @ w_o   (K=256, N=64)
// ---------------------------------------------------------------------------
__global__ __launch_bounds__(256) void kD_out(
    const float* __restrict__ gbuf, const float* __restrict__ o_pre,
    const float* __restrict__ w_o, float* __restrict__ out_chunk, int SCH)
{
    __shared__ float A[128 * 65];
    __shared__ float Bt[64 * 64];
    const int si0 = blockIdx.x * 128;
    const int tid = threadIdx.x;
    const int tx  = tid & 15, ty = tid >> 4;
    float acc[8][4] = {};

    for (int k0 = 0; k0 < HC; k0 += 64) {
        { // A tile = g * o_pre
            const int r = tid >> 1, half = tid & 1;
            const size_t base = (size_t)(si0 + r) * HC + k0 + half * 32;
            float* dst = &A[r * 65 + half * 32];
            #pragma unroll
            for (int e = 0; e < 8; ++e) {
                float4 gg = *reinterpret_cast<const float4*>(gbuf + base + e * 4);
                float4 oo = *reinterpret_cast<const float4*>(o_pre + base + e * 4);
                dst[e * 4 + 0] = gg.x * oo.x; dst[e * 4 + 1] = gg.y * oo.y;
                dst[e * 4 + 2] = gg.z * oo.z; dst[e * 4 + 3] = gg.w * oo.w;
            }
        }
        { // w_o tile
            const int kk = tid >> 2, q = tid & 3;
            #pragma unroll
            for (int e = 0; e < 4; ++e) {
                float4 v4 = *reinterpret_cast<const float4*>(
                    w_o + (size_t)(k0 + kk) * CM + q * 16 + e * 4);
                *reinterpret_cast<float4*>(&Bt[kk * 64 + q * 16 + e * 4]) = v4;
            }
        }
        __syncthreads();
        #pragma unroll 8
        for (int kk = 0; kk < 64; ++kk) {
            float4 b = *reinterpret_cast<float4*>(&Bt[kk * 64 + tx * 4]);
            #pragma unroll
            for (int e = 0; e < 8; ++e) {
                float a = A[(ty * 8 + e) * 65 + kk];
                acc[e][0] += a * b.x; acc[e][1] += a * b.y;
                acc[e][2] += a * b.z; acc[e][3] += a * b.w;
            }
        }
        __syncthreads();
    }
    #pragma unroll
    for (int e = 0; e < 8; ++e) {
        *reinterpret_cast<float4*>(
            &out_chunk[(size_t)(si0 + ty * 8 + e) * CM + tx * 4]) =
            make_float4(acc[e][0], acc[e][1], acc[e][2], acc[e][3]);
    }
}

// ---------------------------------------------------------------------------
extern "C" void kernel_launch(void* const* d_in, const int* in_sizes, int n_in,
                              void* d_out, int out_size, void* d_ws, size_t ws_size,
                              hipStream_t stream)
{
    const float* m        = (const float*)d_in[0];
    const float* z        = (const float*)d_in[1];
    const float* msa_mask = (const float*)d_in[2];
    const float* z_mask   = (const float*)d_in[3];
    const float* ln_m_g   = (const float*)d_in[4];
    const float* ln_m_b   = (const float*)d_in[5];
    const float* w_v      = (const float*)d_in[6];
    const float* w_g      = (const float*)d_in[7];
    const float* ln_z_g   = (const float*)d_in[8];
    const float* ln_z_b   = (const float*)d_in[9];
    const float* w_b      = (const float*)d_in[10];
    const float* w_o      = (const float*)d_in[11];
    float* out = (float*)d_out;

    const size_t wsoft_bytes = (size_t)NH * R_DIM * R_DIM * 2;       // bf16
    // per-chunk bytes: Vt bf16 (SCH*32*8*384*2) + g f32 + o_pre f32
    const size_t per_sch = (size_t)32 * NH * R_DIM * 2
                         + (size_t)R_DIM * HC * 4 * 2;
    int SCH = 256;
    while (SCH > 4 && wsoft_bytes + (size_t)SCH * per_sch > ws_size) SCH >>= 1;

    char* p = (char*)d_ws;
    u16* w_soft = (u16*)p; p += wsoft_bytes;
    u16* Vt     = (u16*)p; p += (size_t)SCH * 32 * NH * R_DIM * 2;
    float* gbuf = (float*)p; p += (size_t)SCH * R_DIM * HC * 4;
    float* obuf = (float*)p;

    kA_bias_softmax<<<R_DIM, 256, 0, stream>>>(z, z_mask, ln_z_g, ln_z_b, w_b, w_soft);

    for (int s0 = 0; s0 < S_DIM; s0 += SCH) {
        kB_proj<<<dim3(8, SCH * 3), 256, 0, stream>>>(
            m + (size_t)s0 * R_DIM * CM, msa_mask + (size_t)s0 * R_DIM,
            ln_m_g, ln_m_b, w_v, w_g, Vt, gbuf, SCH);
        kC_mfma<<<dim3(SCH / 4, 3, NH), 256, 0, stream>>>(w_soft, Vt, obuf, SCH);
        kD_out<<<dim3(SCH * 3), 256, 0, stream>>>(gbuf, obuf, w_o,
                                                  out + (size_t)s0 * R_DIM * CM, SCH);
    }
}

// Round 6
// 464.605 us; speedup vs baseline: 2.6855x; 1.5865x over previous
//
#include <hip/hip_runtime.h>
#include <math.h>

#define S_DIM 512
#define R_DIM 384
#define CM 64
#define CZ 128
#define NH 8
#define CH 32
#define HC 256

typedef unsigned short u16;
typedef __attribute__((ext_vector_type(8))) __bf16 bf16x8;
typedef __attribute__((ext_vector_type(4))) float f32x4;

static __device__ __forceinline__ u16 f2bf(float f) {
    unsigned int u = __float_as_uint(f);
    unsigned int r = (u + 0x7fffu + ((u >> 16) & 1u)) >> 16;
    return (u16)r;
}
static __device__ __forceinline__ float bf2f(u16 h) {
    return __uint_as_float(((unsigned int)h) << 16);
}
static __device__ __forceinline__ void split2(float f, u16& hi, u16& lo) {
    hi = f2bf(f);
    lo = f2bf(f - bf2f(hi));
}

// ---------------------------------------------------------------------------
// Prep: w_v, w_g -> bf16 hi/lo, K-major: wvT[n][c] = w_v[c][n]  (n<256,c<64)
// ---------------------------------------------------------------------------
__global__ __launch_bounds__(256) void kW_prep(
    const float* __restrict__ wv, const float* __restrict__ wg,
    u16* __restrict__ wvT_hi, u16* __restrict__ wvT_lo,
    u16* __restrict__ wgT_hi, u16* __restrict__ wgT_lo)
{
    const int idx = blockIdx.x * 256 + threadIdx.x;   // 2*16384 total
    const int which = idx >> 14;
    const int r = idx & 16383;
    const int n = r >> 6, c = r & 63;
    if (which == 0) split2(wv[c * HC + n], wvT_hi[r], wvT_lo[r]);
    else            split2(wg[c * HC + n], wgT_hi[r], wgT_lo[r]);
}

// ---------------------------------------------------------------------------
// Kernel A: bias = LN(z) @ w_b + INF*(z_mask-1); w = softmax_j(bias)
// one block per i-row; writes w_soft as bf16 [H][R][R] (j contiguous)
// ---------------------------------------------------------------------------
__global__ __launch_bounds__(256) void kA_bias_softmax(
    const float* __restrict__ z, const float* __restrict__ z_mask,
    const float* __restrict__ ln_z_g, const float* __restrict__ ln_z_b,
    const float* __restrict__ w_b, u16* __restrict__ w_soft)
{
    __shared__ float bias_lds[R_DIM * NH];
    __shared__ float znorm[4][CZ];
    const int i    = blockIdx.x;
    const int tid  = threadIdx.x;
    const int wv   = tid >> 6;
    const int lane = tid & 63;

    for (int jj = 0; jj < R_DIM / 4; ++jj) {
        const int j = jj * 4 + wv;
        const float2 zz = *reinterpret_cast<const float2*>(
            z + ((size_t)(i * R_DIM + j)) * CZ + lane * 2);
        float s1 = zz.x + zz.y;
        float s2 = zz.x * zz.x + zz.y * zz.y;
        #pragma unroll
        for (int msk = 32; msk >= 1; msk >>= 1) {
            s1 += __shfl_xor(s1, msk);
            s2 += __shfl_xor(s2, msk);
        }
        const float mu   = s1 * (1.0f / CZ);
        const float var  = s2 * (1.0f / CZ) - mu * mu;
        const float rstd = rsqrtf(var + 1e-5f);
        const int c0 = lane * 2;
        znorm[wv][c0]     = (zz.x - mu) * rstd * ln_z_g[c0]     + ln_z_b[c0];
        znorm[wv][c0 + 1] = (zz.y - mu) * rstd * ln_z_g[c0 + 1] + ln_z_b[c0 + 1];
        __syncthreads();
        const int h = lane & 7, seg = lane >> 3;
        float acc = 0.f;
        #pragma unroll
        for (int t = 0; t < 16; ++t) {
            const int c = seg * 16 + t;
            acc += znorm[wv][c] * w_b[c * NH + h];
        }
        acc += __shfl_xor(acc, 8);
        acc += __shfl_xor(acc, 16);
        acc += __shfl_xor(acc, 32);
        if (seg == 0)
            bias_lds[j * NH + h] = acc + 1e8f * (z_mask[(size_t)i * R_DIM + j] - 1.0f);
        __syncthreads();
    }

    for (int h = wv; h < NH; h += 4) {
        float vals[6];
        float mx = -1e30f;
        #pragma unroll
        for (int u = 0; u < 6; ++u) {
            vals[u] = bias_lds[(lane + u * 64) * NH + h];
            mx = fmaxf(mx, vals[u]);
        }
        #pragma unroll
        for (int msk = 32; msk >= 1; msk >>= 1) mx = fmaxf(mx, __shfl_xor(mx, msk));
        float sum = 0.f;
        #pragma unroll
        for (int u = 0; u < 6; ++u) { vals[u] = __expf(vals[u] - mx); sum += vals[u]; }
        #pragma unroll
        for (int msk = 32; msk >= 1; msk >>= 1) sum += __shfl_xor(sum, msk);
        const float inv = 1.0f / sum;
        #pragma unroll
        for (int u = 0; u < 6; ++u)
            w_soft[((size_t)h * R_DIM + i) * R_DIM + lane + u * 64] =
                f2bf(vals[u] * inv);
    }
}

// ---------------------------------------------------------------------------
// Kernel B (split-MFMA): LN(m) rows -> hi/lo bf16; GEMM vs split wvT/wgT.
// acc = ah*bh + al*bh + ah*bl  (~f32 accurate)
// panel 0,1: V cols 0-127/128-255 -> masked, Vt[h][n][j] bf16
// panel 2,3: G cols 0-127/128-255 -> sigmoid, gbuf[si][k] f32
// ---------------------------------------------------------------------------
__global__ __launch_bounds__(256) void kB_mfma(
    const float* __restrict__ m_chunk, const float* __restrict__ mask_chunk,
    const float* __restrict__ ln_g, const float* __restrict__ ln_b,
    const u16* __restrict__ wvT_hi, const u16* __restrict__ wvT_lo,
    const u16* __restrict__ wgT_hi, const u16* __restrict__ wgT_lo,
    u16* __restrict__ Vt, float* __restrict__ gbuf, int SCH)
{
    __shared__ __align__(16) u16 smem[4 * 128 * 72];   // 73728 B
    u16* a_hi = smem;                  // [128][72]
    u16* a_lo = smem + 128 * 72;
    u16* b_hi = smem + 2 * 128 * 72;
    u16* b_lo = smem + 3 * 128 * 72;
    const int tid   = threadIdx.x;
    const int panel = blockIdx.x;      // 0,1 -> V ; 2,3 -> G
    const int si0   = blockIdx.y * 128;
    const int n0    = (panel & 1) * 128;
    const int lane  = tid & 63;
    const int w     = tid >> 6;
    const int wr    = (w >> 1) * 64, wc = (w & 1) * 64;

    { // A: load 128 m rows, LN (pairs of threads per row), split hi/lo
        const int r = tid >> 1, half = tid & 1;
        const float* src = m_chunk + (size_t)(si0 + r) * CM + half * 32;
        float x[32];
        float s1 = 0.f, s2 = 0.f;
        #pragma unroll
        for (int e = 0; e < 8; ++e) {
            float4 v4 = *reinterpret_cast<const float4*>(src + e * 4);
            x[e*4+0] = v4.x; x[e*4+1] = v4.y; x[e*4+2] = v4.z; x[e*4+3] = v4.w;
            s1 += v4.x + v4.y + v4.z + v4.w;
            s2 += v4.x*v4.x + v4.y*v4.y + v4.z*v4.z + v4.w*v4.w;
        }
        s1 += __shfl_xor(s1, 1);
        s2 += __shfl_xor(s2, 1);
        const float mu   = s1 * (1.f / 64);
        const float var  = s2 * (1.f / 64) - mu * mu;
        const float rstd = rsqrtf(var + 1e-5f);
        #pragma unroll
        for (int e = 0; e < 8; ++e) {
            #pragma unroll
            for (int q = 0; q < 4; ++q) {
                const int c = half * 32 + e * 4 + q;
                const float v = (x[e*4+q] - mu) * rstd * ln_g[c] + ln_b[c];
                split2(v, a_hi[r * 72 + c], a_lo[r * 72 + c]);
            }
        }
    }
    { // B: 128 weight rows (n0..n0+127), K=64 contiguous, hi/lo
        const u16* Wh = (panel < 2 ? wvT_hi : wgT_hi) + (size_t)n0 * 64;
        const u16* Wl = (panel < 2 ? wvT_lo : wgT_lo) + (size_t)n0 * 64;
        #pragma unroll
        for (int e = 0; e < 4; ++e) {
            const int c = e * 256 + tid;          // 0..1023
            const int row = c >> 3, off = (c & 7) * 8;
            *reinterpret_cast<uint4*>(&b_hi[row * 72 + off]) =
                *reinterpret_cast<const uint4*>(Wh + row * 64 + off);
            *reinterpret_cast<uint4*>(&b_lo[row * 72 + off]) =
                *reinterpret_cast<const uint4*>(Wl + row * 64 + off);
        }
    }
    __syncthreads();

    f32x4 acc[4][4] = {};
    #pragma unroll
    for (int ks = 0; ks < 2; ++ks) {
        const int ko = ks * 32 + (lane >> 4) * 8;
        bf16x8 ah[4], al[4], bh[4], bl[4];
        #pragma unroll
        for (int mm = 0; mm < 4; ++mm) {
            const int base = (wr + mm * 16 + (lane & 15)) * 72 + ko;
            ah[mm] = *reinterpret_cast<const bf16x8*>(&a_hi[base]);
            al[mm] = *reinterpret_cast<const bf16x8*>(&a_lo[base]);
        }
        #pragma unroll
        for (int nn = 0; nn < 4; ++nn) {
            const int base = (wc + nn * 16 + (lane & 15)) * 72 + ko;
            bh[nn] = *reinterpret_cast<const bf16x8*>(&b_hi[base]);
            bl[nn] = *reinterpret_cast<const bf16x8*>(&b_lo[base]);
        }
        #pragma unroll
        for (int mm = 0; mm < 4; ++mm)
            #pragma unroll
            for (int nn = 0; nn < 4; ++nn) {
                acc[mm][nn] = __builtin_amdgcn_mfma_f32_16x16x32_bf16(
                    ah[mm], bh[nn], acc[mm][nn], 0, 0, 0);
                acc[mm][nn] = __builtin_amdgcn_mfma_f32_16x16x32_bf16(
                    al[mm], bh[nn], acc[mm][nn], 0, 0, 0);
                acc[mm][nn] = __builtin_amdgcn_mfma_f32_16x16x32_bf16(
                    ah[mm], bl[nn], acc[mm][nn], 0, 0, 0);
            }
    }

    __syncthreads();                   // reuse smem as transpose buffer
    const int r4 = (lane >> 4) * 4, cl = lane & 15;
    if (panel < 2) {
        // V: mask rows, transpose to [n][j-local], bf16
        u16* T = smem;                 // [128 n][136 j]
        #pragma unroll
        for (int mm = 0; mm < 4; ++mm) {
            const int rowb = wr + mm * 16 + r4;
            const float4 mk = *reinterpret_cast<const float4*>(mask_chunk + si0 + rowb);
            #pragma unroll
            for (int nn = 0; nn < 4; ++nn) {
                const int n = wc + nn * 16 + cl;
                ushort4 pk;
                pk.x = f2bf(acc[mm][nn][0] * mk.x);
                pk.y = f2bf(acc[mm][nn][1] * mk.y);
                pk.z = f2bf(acc[mm][nn][2] * mk.z);
                pk.w = f2bf(acc[mm][nn][3] * mk.w);
                *reinterpret_cast<ushort4*>(&T[n * 136 + rowb]) = pk;
            }
        }
        __syncthreads();
        const int sc = si0 / R_DIM, j0 = si0 % R_DIM;
        const size_t Nn = (size_t)SCH * 32;
        #pragma unroll
        for (int e = 0; e < 8; ++e) {
            const int c = e * 256 + tid;          // 0..2047
            const int n = c >> 4, part = c & 15;
            const int k = n0 + n;
            const int h = k >> 5, cc = k & 31;
            u16* dst = Vt + ((size_t)h * Nn + (size_t)sc * 32 + cc) * R_DIM
                         + j0 + part * 8;
            *reinterpret_cast<uint4*>(dst) =
                *reinterpret_cast<const uint4*>(&T[n * 136 + part * 8]);
        }
    } else {
        // G: sigmoid, f32, natural [si][k] layout
        float* T = reinterpret_cast<float*>(smem);   // [128 si][136 k] f32
        #pragma unroll
        for (int mm = 0; mm < 4; ++mm) {
            const int rowb = wr + mm * 16 + r4;
            #pragma unroll
            for (int nn = 0; nn < 4; ++nn) {
                const int n = wc + nn * 16 + cl;
                #pragma unroll
                for (int r = 0; r < 4; ++r)
                    T[(rowb + r) * 136 + n] = 1.f / (1.f + __expf(-acc[mm][nn][r]));
            }
        }
        __syncthreads();
        #pragma unroll
        for (int e = 0; e < 16; ++e) {
            const int c = e * 256 + tid;          // 0..4095
            const int row = c >> 5, part = c & 31;
            *reinterpret_cast<float4*>(
                &gbuf[(size_t)(si0 + row) * HC + n0 + part * 4]) =
                *reinterpret_cast<const float4*>(&T[row * 136 + part * 4]);
        }
    }
}

// ---------------------------------------------------------------------------
// Kernel C: per-head MFMA GEMM  o_pre[i,n] = sum_j W_h[i,j] * V_h[j,n]
// writes o_pre f32 [sc*R + i][h*32+c]   (proven in round 3)
// ---------------------------------------------------------------------------
__global__ __launch_bounds__(256) void kC_mfma(
    const u16* __restrict__ Wsoft, const u16* __restrict__ Vt,
    float* __restrict__ o_pre, int SCH)
{
    constexpr int LDSP = 40;
    __shared__ __align__(16) u16 lds_a[128 * LDSP];
    __shared__ __align__(16) u16 lds_b[128 * LDSP];
    const int N   = SCH * 32;
    const int n0  = blockIdx.x * 128;
    const int i0  = blockIdx.y * 128;
    const int h   = blockIdx.z;
    const int tid = threadIdx.x;
    const int lane = tid & 63;
    const int w    = tid >> 6;
    const int wr   = (w >> 1) * 64;
    const int wc   = (w & 1) * 64;

    const u16* Wp = Wsoft + (size_t)h * R_DIM * R_DIM;
    const u16* Vp = Vt    + (size_t)h * N * R_DIM;

    f32x4 acc[4][4] = {};

    for (int k0 = 0; k0 < R_DIM; k0 += 32) {
        __syncthreads();
        #pragma unroll
        for (int rep = 0; rep < 2; ++rep) {
            const int c = rep * 256 + tid;
            const int row = c >> 2, q = c & 3;
            uint4 va = *reinterpret_cast<const uint4*>(
                Wp + (size_t)(i0 + row) * R_DIM + k0 + q * 8);
            *reinterpret_cast<uint4*>(&lds_a[row * LDSP + q * 8]) = va;
            uint4 vb = *reinterpret_cast<const uint4*>(
                Vp + (size_t)(n0 + row) * R_DIM + k0 + q * 8);
            *reinterpret_cast<uint4*>(&lds_b[row * LDSP + q * 8]) = vb;
        }
        __syncthreads();

        bf16x8 afrag[4], bfrag[4];
        #pragma unroll
        for (int mm = 0; mm < 4; ++mm) {
            const int row = wr + mm * 16 + (lane & 15);
            afrag[mm] = *reinterpret_cast<const bf16x8*>(
                &lds_a[row * LDSP + (lane >> 4) * 8]);
        }
        #pragma unroll
        for (int nn = 0; nn < 4; ++nn) {
            const int row = wc + nn * 16 + (lane & 15);
            bfrag[nn] = *reinterpret_cast<const bf16x8*>(
                &lds_b[row * LDSP + (lane >> 4) * 8]);
        }
        #pragma unroll
        for (int mm = 0; mm < 4; ++mm)
            #pragma unroll
            for (int nn = 0; nn < 4; ++nn)
                acc[mm][nn] = __builtin_amdgcn_mfma_f32_16x16x32_bf16(
                    afrag[mm], bfrag[nn], acc[mm][nn], 0, 0, 0);
    }

    const int r4 = (lane >> 4) * 4;
    const int cl = lane & 15;
    #pragma unroll
    for (int mm = 0; mm < 4; ++mm) {
        #pragma unroll
        for (int nn = 0; nn < 4; ++nn) {
            const int i = i0 + wr + mm * 16 + r4;
            const int n = n0 + wc + nn * 16 + cl;
            const int sc = n >> 5, cc = n & 31;
            float* dst = &o_pre[((size_t)sc * R_DIM + i) * HC + h * 32 + cc];
            #pragma unroll
            for (int r = 0; r < 4; ++r)
                dst[(size_t)r * HC] = acc[mm][nn][r];
        }
    }
}

// ---------------------------------------------------------------------------
// Kernel D: out[si, :] = (g[si,:] * o_pre[si,:]) @ w_o  (K=256, N=64)
// fp32 VALU version — proven in round 3 (absmax 4.88e-4).
// ---------------------------------------------------------------------------
__global__ __launch_bounds__(256) void kD_out(
    const float* __restrict__ gbuf, const float* __restrict__ o_pre,
    const float* __restrict__ w_o, float* __restrict__ out_chunk, int SCH)
{
    __shared__ float A[128 * 65];
    __shared__ float Bt[64 * 64];
    const int si0 = blockIdx.x * 128;
    const int tid = threadIdx.x;
    const int tx  = tid & 15, ty = tid >> 4;
    float acc[8][4] = {};

    for (int k0 = 0; k0 < HC; k0 += 64) {
        { // A tile = g * o_pre
            const int r = tid >> 1, half = tid & 1;
            const size_t base = (size_t)(si0 + r) * HC + k0 + half * 32;
            float* dst = &A[r * 65 + half * 32];
            #pragma unroll
            for (int e = 0; e < 8; ++e) {
                float4 gg = *reinterpret_cast<const float4*>(gbuf + base + e * 4);
                float4 oo = *reinterpret_cast<const float4*>(o_pre + base + e * 4);
                dst[e * 4 + 0] = gg.x * oo.x; dst[e * 4 + 1] = gg.y * oo.y;
                dst[e * 4 + 2] = gg.z * oo.z; dst[e * 4 + 3] = gg.w * oo.w;
            }
        }
        { // w_o tile
            const int kk = tid >> 2, q = tid & 3;
            #pragma unroll
            for (int e = 0; e < 4; ++e) {
                float4 v4 = *reinterpret_cast<const float4*>(
                    w_o + (size_t)(k0 + kk) * CM + q * 16 + e * 4);
                *reinterpret_cast<float4*>(&Bt[kk * 64 + q * 16 + e * 4]) = v4;
            }
        }
        __syncthreads();
        #pragma unroll 8
        for (int kk = 0; kk < 64; ++kk) {
            float4 b = *reinterpret_cast<float4*>(&Bt[kk * 64 + tx * 4]);
            #pragma unroll
            for (int e = 0; e < 8; ++e) {
                float a = A[(ty * 8 + e) * 65 + kk];
                acc[e][0] += a * b.x; acc[e][1] += a * b.y;
                acc[e][2] += a * b.z; acc[e][3] += a * b.w;
            }
        }
        __syncthreads();
    }
    #pragma unroll
    for (int e = 0; e < 8; ++e) {
        *reinterpret_cast<float4*>(
            &out_chunk[(size_t)(si0 + ty * 8 + e) * CM + tx * 4]) =
            make_float4(acc[e][0], acc[e][1], acc[e][2], acc[e][3]);
    }
}

// ---------------------------------------------------------------------------
extern "C" void kernel_launch(void* const* d_in, const int* in_sizes, int n_in,
                              void* d_out, int out_size, void* d_ws, size_t ws_size,
                              hipStream_t stream)
{
    const float* m        = (const float*)d_in[0];
    const float* z        = (const float*)d_in[1];
    const float* msa_mask = (const float*)d_in[2];
    const float* z_mask   = (const float*)d_in[3];
    const float* ln_m_g   = (const float*)d_in[4];
    const float* ln_m_b   = (const float*)d_in[5];
    const float* w_v      = (const float*)d_in[6];
    const float* w_g      = (const float*)d_in[7];
    const float* ln_z_g   = (const float*)d_in[8];
    const float* ln_z_b   = (const float*)d_in[9];
    const float* w_b      = (const float*)d_in[10];
    const float* w_o      = (const float*)d_in[11];
    float* out = (float*)d_out;

    const size_t wsoft_bytes = (size_t)NH * R_DIM * R_DIM * 2;       // bf16
    const size_t wts_bytes   = 4 * 16384 * 2;                        // wv/wg hi+lo
    // per s-row: Vt bf16 + g f32 + o_pre f32
    const size_t per_sch = (size_t)R_DIM * HC * (2 + 4 + 4);
    int SCH = 256;
    while (SCH > 4 && wsoft_bytes + wts_bytes + (size_t)SCH * per_sch > ws_size)
        SCH >>= 1;

    char* p = (char*)d_ws;
    u16* w_soft  = (u16*)p; p += wsoft_bytes;
    u16* wvT_hi  = (u16*)p; p += 16384 * 2;
    u16* wvT_lo  = (u16*)p; p += 16384 * 2;
    u16* wgT_hi  = (u16*)p; p += 16384 * 2;
    u16* wgT_lo  = (u16*)p; p += 16384 * 2;
    u16* Vt      = (u16*)p; p += (size_t)SCH * 32 * NH * R_DIM * 2;
    float* gbuf  = (float*)p; p += (size_t)SCH * R_DIM * HC * 4;
    float* obuf  = (float*)p;

    kW_prep<<<128, 256, 0, stream>>>(w_v, w_g, wvT_hi, wvT_lo, wgT_hi, wgT_lo);
    kA_bias_softmax<<<R_DIM, 256, 0, stream>>>(z, z_mask, ln_z_g, ln_z_b, w_b, w_soft);

    for (int s0 = 0; s0 < S_DIM; s0 += SCH) {
        kB_mfma<<<dim3(4, SCH * 3), 256, 0, stream>>>(
            m + (size_t)s0 * R_DIM * CM, msa_mask + (size_t)s0 * R_DIM,
            ln_m_g, ln_m_b, wvT_hi, wvT_lo, wgT_hi, wgT_lo, Vt, gbuf, SCH);
        kC_mfma<<<dim3(SCH / 4, 3, NH), 256, 0, stream>>>(w_soft, Vt, obuf, SCH);
        kD_out<<<dim3(SCH * 3), 256, 0, stream>>>(gbuf, obuf, w_o,
                                                  out + (size_t)s0 * R_DIM * CM, SCH);
    }
}

// Round 7
// 429.990 us; speedup vs baseline: 2.9017x; 1.0805x over previous
//
#include <hip/hip_runtime.h>
#include <math.h>

#define S_DIM 512
#define R_DIM 384
#define CM 64
#define CZ 128
#define NH 8
#define CH 32
#define HC 256

typedef unsigned short u16;
typedef __attribute__((ext_vector_type(8))) __bf16 bf16x8;
typedef __attribute__((ext_vector_type(4))) float f32x4;

static __device__ __forceinline__ u16 f2bf(float f) {
    unsigned int u = __float_as_uint(f);
    unsigned int r = (u + 0x7fffu + ((u >> 16) & 1u)) >> 16;
    return (u16)r;
}
static __device__ __forceinline__ float bf2f(u16 h) {
    return __uint_as_float(((unsigned int)h) << 16);
}
static __device__ __forceinline__ void split2(float f, u16& hi, u16& lo) {
    hi = f2bf(f);
    lo = f2bf(f - bf2f(hi));
}

// ---------------------------------------------------------------------------
// Prep: w_v, w_g -> bf16 hi/lo, K-major: wvT[n][c] = w_v[c][n]  (n<256,c<64)
// ---------------------------------------------------------------------------
__global__ __launch_bounds__(256) void kW_prep(
    const float* __restrict__ wv, const float* __restrict__ wg,
    u16* __restrict__ wvT_hi, u16* __restrict__ wvT_lo,
    u16* __restrict__ wgT_hi, u16* __restrict__ wgT_lo)
{
    const int idx = blockIdx.x * 256 + threadIdx.x;   // 2*16384 total
    const int which = idx >> 14;
    const int r = idx & 16383;
    const int n = r >> 6, c = r & 63;
    if (which == 0) split2(wv[c * HC + n], wvT_hi[r], wvT_lo[r]);
    else            split2(wg[c * HC + n], wgT_hi[r], wgT_lo[r]);
}

// ---------------------------------------------------------------------------
// Kernel A1: bias[h][i][j] = LN(z[i,j,:]) @ w_b[:,h] + INF*(z_mask-1)
// one wave per (i,j) row; fully parallel, one barrier per block.
// ---------------------------------------------------------------------------
__global__ __launch_bounds__(256) void kA1_bias(
    const float* __restrict__ z, const float* __restrict__ z_mask,
    const float* __restrict__ ln_z_g, const float* __restrict__ ln_z_b,
    const float* __restrict__ w_b, float* __restrict__ bias_ws)
{
    __shared__ float wb_s[CZ * NH];      // 4 KB
    __shared__ float zn_s[4][CZ];        // 2 KB
    const int tid = threadIdx.x, w = tid >> 6, lane = tid & 63;
    const int ridx = blockIdx.x * 4 + w;          // i*R + j

    #pragma unroll
    for (int q = 0; q < 4; ++q) wb_s[tid * 4 + q] = w_b[tid * 4 + q];

    const float2 zz = *reinterpret_cast<const float2*>(
        z + (size_t)ridx * CZ + lane * 2);
    float s1 = zz.x + zz.y;
    float s2 = zz.x * zz.x + zz.y * zz.y;
    #pragma unroll
    for (int msk = 32; msk >= 1; msk >>= 1) {
        s1 += __shfl_xor(s1, msk);
        s2 += __shfl_xor(s2, msk);
    }
    const float mu   = s1 * (1.0f / CZ);
    const float var  = s2 * (1.0f / CZ) - mu * mu;
    const float rstd = rsqrtf(var + 1e-5f);
    const int c0 = lane * 2;
    zn_s[w][c0]     = (zz.x - mu) * rstd * ln_z_g[c0]     + ln_z_b[c0];
    zn_s[w][c0 + 1] = (zz.y - mu) * rstd * ln_z_g[c0 + 1] + ln_z_b[c0 + 1];
    __syncthreads();

    const int h = lane & 7, seg = lane >> 3;
    float acc = 0.f;
    #pragma unroll
    for (int t = 0; t < 16; ++t) {
        const int c = seg * 16 + t;
        acc += zn_s[w][c] * wb_s[c * NH + h];
    }
    acc += __shfl_xor(acc, 8);
    acc += __shfl_xor(acc, 16);
    acc += __shfl_xor(acc, 32);
    if (seg == 0)
        bias_ws[(size_t)h * R_DIM * R_DIM + ridx] =
            acc + 1e8f * (z_mask[ridx] - 1.0f);
}

// ---------------------------------------------------------------------------
// Kernel A2: w_soft[h][i][j] = softmax_j(bias[h][i][j]) -> bf16
// one wave per (h,i) row.
// ---------------------------------------------------------------------------
__global__ __launch_bounds__(256) void kA2_softmax(
    const float* __restrict__ bias_ws, u16* __restrict__ w_soft)
{
    const int tid = threadIdx.x, w = tid >> 6, lane = tid & 63;
    const int row = blockIdx.x * 4 + w;           // h*R + i
    const float* src = bias_ws + (size_t)row * R_DIM;
    float vals[6];
    float mx = -1e30f;
    #pragma unroll
    for (int u = 0; u < 6; ++u) {
        vals[u] = src[lane + u * 64];
        mx = fmaxf(mx, vals[u]);
    }
    #pragma unroll
    for (int msk = 32; msk >= 1; msk >>= 1) mx = fmaxf(mx, __shfl_xor(mx, msk));
    float sum = 0.f;
    #pragma unroll
    for (int u = 0; u < 6; ++u) { vals[u] = __expf(vals[u] - mx); sum += vals[u]; }
    #pragma unroll
    for (int msk = 32; msk >= 1; msk >>= 1) sum += __shfl_xor(sum, msk);
    const float inv = 1.0f / sum;
    u16* dst = w_soft + (size_t)row * R_DIM;
    #pragma unroll
    for (int u = 0; u < 6; ++u)
        dst[lane + u * 64] = f2bf(vals[u] * inv);
}

// ---------------------------------------------------------------------------
// Kernel B (split-MFMA): LN(m) rows -> hi/lo bf16; GEMM vs split wvT/wgT.
// acc = ah*bh + al*bh + ah*bl  (~f32 accurate)
// panel 0,1: V cols 0-127/128-255 -> masked, Vt[h][n][j] bf16
// panel 2,3: G cols 0-127/128-255 -> sigmoid, gbuf[si][k] f32
// ---------------------------------------------------------------------------
__global__ __launch_bounds__(256) void kB_mfma(
    const float* __restrict__ m_chunk, const float* __restrict__ mask_chunk,
    const float* __restrict__ ln_g, const float* __restrict__ ln_b,
    const u16* __restrict__ wvT_hi, const u16* __restrict__ wvT_lo,
    const u16* __restrict__ wgT_hi, const u16* __restrict__ wgT_lo,
    u16* __restrict__ Vt, float* __restrict__ gbuf, int SCH)
{
    __shared__ __align__(16) u16 smem[4 * 128 * 72];   // 73728 B
    u16* a_hi = smem;                  // [128][72]
    u16* a_lo = smem + 128 * 72;
    u16* b_hi = smem + 2 * 128 * 72;
    u16* b_lo = smem + 3 * 128 * 72;
    const int tid   = threadIdx.x;
    const int panel = blockIdx.x;      // 0,1 -> V ; 2,3 -> G
    const int si0   = blockIdx.y * 128;
    const int n0    = (panel & 1) * 128;
    const int lane  = tid & 63;
    const int w     = tid >> 6;
    const int wr    = (w >> 1) * 64, wc = (w & 1) * 64;

    { // A: load 128 m rows, LN (pairs of threads per row), split hi/lo
        const int r = tid >> 1, half = tid & 1;
        const float* src = m_chunk + (size_t)(si0 + r) * CM + half * 32;
        float x[32];
        float s1 = 0.f, s2 = 0.f;
        #pragma unroll
        for (int e = 0; e < 8; ++e) {
            float4 v4 = *reinterpret_cast<const float4*>(src + e * 4);
            x[e*4+0] = v4.x; x[e*4+1] = v4.y; x[e*4+2] = v4.z; x[e*4+3] = v4.w;
            s1 += v4.x + v4.y + v4.z + v4.w;
            s2 += v4.x*v4.x + v4.y*v4.y + v4.z*v4.z + v4.w*v4.w;
        }
        s1 += __shfl_xor(s1, 1);
        s2 += __shfl_xor(s2, 1);
        const float mu   = s1 * (1.f / 64);
        const float var  = s2 * (1.f / 64) - mu * mu;
        const float rstd = rsqrtf(var + 1e-5f);
        #pragma unroll
        for (int e = 0; e < 8; ++e) {
            #pragma unroll
            for (int q = 0; q < 4; ++q) {
                const int c = half * 32 + e * 4 + q;
                const float v = (x[e*4+q] - mu) * rstd * ln_g[c] + ln_b[c];
                split2(v, a_hi[r * 72 + c], a_lo[r * 72 + c]);
            }
        }
    }
    { // B: 128 weight rows (n0..n0+127), K=64 contiguous, hi/lo
        const u16* Wh = (panel < 2 ? wvT_hi : wgT_hi) + (size_t)n0 * 64;
        const u16* Wl = (panel < 2 ? wvT_lo : wgT_lo) + (size_t)n0 * 64;
        #pragma unroll
        for (int e = 0; e < 4; ++e) {
            const int c = e * 256 + tid;          // 0..1023
            const int row = c >> 3, off = (c & 7) * 8;
            *reinterpret_cast<uint4*>(&b_hi[row * 72 + off]) =
                *reinterpret_cast<const uint4*>(Wh + row * 64 + off);
            *reinterpret_cast<uint4*>(&b_lo[row * 72 + off]) =
                *reinterpret_cast<const uint4*>(Wl + row * 64 + off);
        }
    }
    __syncthreads();

    f32x4 acc[4][4] = {};
    #pragma unroll
    for (int ks = 0; ks < 2; ++ks) {
        const int ko = ks * 32 + (lane >> 4) * 8;
        bf16x8 ah[4], al[4], bh[4], bl[4];
        #pragma unroll
        for (int mm = 0; mm < 4; ++mm) {
            const int base = (wr + mm * 16 + (lane & 15)) * 72 + ko;
            ah[mm] = *reinterpret_cast<const bf16x8*>(&a_hi[base]);
            al[mm] = *reinterpret_cast<const bf16x8*>(&a_lo[base]);
        }
        #pragma unroll
        for (int nn = 0; nn < 4; ++nn) {
            const int base = (wc + nn * 16 + (lane & 15)) * 72 + ko;
            bh[nn] = *reinterpret_cast<const bf16x8*>(&b_hi[base]);
            bl[nn] = *reinterpret_cast<const bf16x8*>(&b_lo[base]);
        }
        #pragma unroll
        for (int mm = 0; mm < 4; ++mm)
            #pragma unroll
            for (int nn = 0; nn < 4; ++nn) {
                acc[mm][nn] = __builtin_amdgcn_mfma_f32_16x16x32_bf16(
                    ah[mm], bh[nn], acc[mm][nn], 0, 0, 0);
                acc[mm][nn] = __builtin_amdgcn_mfma_f32_16x16x32_bf16(
                    al[mm], bh[nn], acc[mm][nn], 0, 0, 0);
                acc[mm][nn] = __builtin_amdgcn_mfma_f32_16x16x32_bf16(
                    ah[mm], bl[nn], acc[mm][nn], 0, 0, 0);
            }
    }

    __syncthreads();                   // reuse smem as transpose buffer
    const int r4 = (lane >> 4) * 4, cl = lane & 15;
    if (panel < 2) {
        // V: mask rows, transpose to [n][j-local], bf16
        u16* T = smem;                 // [128 n][136 j]
        #pragma unroll
        for (int mm = 0; mm < 4; ++mm) {
            const int rowb = wr + mm * 16 + r4;
            const float4 mk = *reinterpret_cast<const float4*>(mask_chunk + si0 + rowb);
            #pragma unroll
            for (int nn = 0; nn < 4; ++nn) {
                const int n = wc + nn * 16 + cl;
                ushort4 pk;
                pk.x = f2bf(acc[mm][nn][0] * mk.x);
                pk.y = f2bf(acc[mm][nn][1] * mk.y);
                pk.z = f2bf(acc[mm][nn][2] * mk.z);
                pk.w = f2bf(acc[mm][nn][3] * mk.w);
                *reinterpret_cast<ushort4*>(&T[n * 136 + rowb]) = pk;
            }
        }
        __syncthreads();
        const int sc = si0 / R_DIM, j0 = si0 % R_DIM;
        const size_t Nn = (size_t)SCH * 32;
        #pragma unroll
        for (int e = 0; e < 8; ++e) {
            const int c = e * 256 + tid;          // 0..2047
            const int n = c >> 4, part = c & 15;
            const int k = n0 + n;
            const int h = k >> 5, cc = k & 31;
            u16* dst = Vt + ((size_t)h * Nn + (size_t)sc * 32 + cc) * R_DIM
                         + j0 + part * 8;
            *reinterpret_cast<uint4*>(dst) =
                *reinterpret_cast<const uint4*>(&T[n * 136 + part * 8]);
        }
    } else {
        // G: sigmoid, f32, natural [si][k] layout
        float* T = reinterpret_cast<float*>(smem);   // [128 si][136 k] f32
        #pragma unroll
        for (int mm = 0; mm < 4; ++mm) {
            const int rowb = wr + mm * 16 + r4;
            #pragma unroll
            for (int nn = 0; nn < 4; ++nn) {
                const int n = wc + nn * 16 + cl;
                #pragma unroll
                for (int r = 0; r < 4; ++r)
                    T[(rowb + r) * 136 + n] = 1.f / (1.f + __expf(-acc[mm][nn][r]));
            }
        }
        __syncthreads();
        #pragma unroll
        for (int e = 0; e < 16; ++e) {
            const int c = e * 256 + tid;          // 0..4095
            const int row = c >> 5, part = c & 31;
            *reinterpret_cast<float4*>(
                &gbuf[(size_t)(si0 + row) * HC + n0 + part * 4]) =
                *reinterpret_cast<const float4*>(&T[row * 136 + part * 4]);
        }
    }
}

// ---------------------------------------------------------------------------
// Kernel C: per-head MFMA GEMM  o_pre[i,n] = sum_j W_h[i,j] * V_h[j,n]
// writes o_pre f32 [sc*R + i][h*32+c]   (proven in round 3)
// ---------------------------------------------------------------------------
__global__ __launch_bounds__(256) void kC_mfma(
    const u16* __restrict__ Wsoft, const u16* __restrict__ Vt,
    float* __restrict__ o_pre, int SCH)
{
    constexpr int LDSP = 40;
    __shared__ __align__(16) u16 lds_a[128 * LDSP];
    __shared__ __align__(16) u16 lds_b[128 * LDSP];
    const int N   = SCH * 32;
    const int n0  = blockIdx.x * 128;
    const int i0  = blockIdx.y * 128;
    const int h   = blockIdx.z;
    const int tid = threadIdx.x;
    const int lane = tid & 63;
    const int w    = tid >> 6;
    const int wr   = (w >> 1) * 64;
    const int wc   = (w & 1) * 64;

    const u16* Wp = Wsoft + (size_t)h * R_DIM * R_DIM;
    const u16* Vp = Vt    + (size_t)h * N * R_DIM;

    f32x4 acc[4][4] = {};

    for (int k0 = 0; k0 < R_DIM; k0 += 32) {
        __syncthreads();
        #pragma unroll
        for (int rep = 0; rep < 2; ++rep) {
            const int c = rep * 256 + tid;
            const int row = c >> 2, q = c & 3;
            uint4 va = *reinterpret_cast<const uint4*>(
                Wp + (size_t)(i0 + row) * R_DIM + k0 + q * 8);
            *reinterpret_cast<uint4*>(&lds_a[row * LDSP + q * 8]) = va;
            uint4 vb = *reinterpret_cast<const uint4*>(
                Vp + (size_t)(n0 + row) * R_DIM + k0 + q * 8);
            *reinterpret_cast<uint4*>(&lds_b[row * LDSP + q * 8]) = vb;
        }
        __syncthreads();

        bf16x8 afrag[4], bfrag[4];
        #pragma unroll
        for (int mm = 0; mm < 4; ++mm) {
            const int row = wr + mm * 16 + (lane & 15);
            afrag[mm] = *reinterpret_cast<const bf16x8*>(
                &lds_a[row * LDSP + (lane >> 4) * 8]);
        }
        #pragma unroll
        for (int nn = 0; nn < 4; ++nn) {
            const int row = wc + nn * 16 + (lane & 15);
            bfrag[nn] = *reinterpret_cast<const bf16x8*>(
                &lds_b[row * LDSP + (lane >> 4) * 8]);
        }
        #pragma unroll
        for (int mm = 0; mm < 4; ++mm)
            #pragma unroll
            for (int nn = 0; nn < 4; ++nn)
                acc[mm][nn] = __builtin_amdgcn_mfma_f32_16x16x32_bf16(
                    afrag[mm], bfrag[nn], acc[mm][nn], 0, 0, 0);
    }

    const int r4 = (lane >> 4) * 4;
    const int cl = lane & 15;
    #pragma unroll
    for (int mm = 0; mm < 4; ++mm) {
        #pragma unroll
        for (int nn = 0; nn < 4; ++nn) {
            const int i = i0 + wr + mm * 16 + r4;
            const int n = n0 + wc + nn * 16 + cl;
            const int sc = n >> 5, cc = n & 31;
            float* dst = &o_pre[((size_t)sc * R_DIM + i) * HC + h * 32 + cc];
            #pragma unroll
            for (int r = 0; r < 4; ++r)
                dst[(size_t)r * HC] = acc[mm][nn][r];
        }
    }
}

// ---------------------------------------------------------------------------
// Kernel D: out[si, :] = (g[si,:] * o_pre[si,:]) @ w_o  (K=256, N=64)
// fp32 VALU version — proven in round 3 (absmax 4.88e-4).
// ---------------------------------------------------------------------------
__global__ __launch_bounds__(256) void kD_out(
    const float* __restrict__ gbuf, const float* __restrict__ o_pre,
    const float* __restrict__ w_o, float* __restrict__ out_chunk, int SCH)
{
    __shared__ float A[128 * 65];
    __shared__ float Bt[64 * 64];
    const int si0 = blockIdx.x * 128;
    const int tid = threadIdx.x;
    const int tx  = tid & 15, ty = tid >> 4;
    float acc[8][4] = {};

    for (int k0 = 0; k0 < HC; k0 += 64) {
        { // A tile = g * o_pre
            const int r = tid >> 1, half = tid & 1;
            const size_t base = (size_t)(si0 + r) * HC + k0 + half * 32;
            float* dst = &A[r * 65 + half * 32];
            #pragma unroll
            for (int e = 0; e < 8; ++e) {
                float4 gg = *reinterpret_cast<const float4*>(gbuf + base + e * 4);
                float4 oo = *reinterpret_cast<const float4*>(o_pre + base + e * 4);
                dst[e * 4 + 0] = gg.x * oo.x; dst[e * 4 + 1] = gg.y * oo.y;
                dst[e * 4 + 2] = gg.z * oo.z; dst[e * 4 + 3] = gg.w * oo.w;
            }
        }
        { // w_o tile
            const int kk = tid >> 2, q = tid & 3;
            #pragma unroll
            for (int e = 0; e < 4; ++e) {
                float4 v4 = *reinterpret_cast<const float4*>(
                    w_o + (size_t)(k0 + kk) * CM + q * 16 + e * 4);
                *reinterpret_cast<float4*>(&Bt[kk * 64 + q * 16 + e * 4]) = v4;
            }
        }
        __syncthreads();
        #pragma unroll 8
        for (int kk = 0; kk < 64; ++kk) {
            float4 b = *reinterpret_cast<float4*>(&Bt[kk * 64 + tx * 4]);
            #pragma unroll
            for (int e = 0; e < 8; ++e) {
                float a = A[(ty * 8 + e) * 65 + kk];
                acc[e][0] += a * b.x; acc[e][1] += a * b.y;
                acc[e][2] += a * b.z; acc[e][3] += a * b.w;
            }
        }
        __syncthreads();
    }
    #pragma unroll
    for (int e = 0; e < 8; ++e) {
        *reinterpret_cast<float4*>(
            &out_chunk[(size_t)(si0 + ty * 8 + e) * CM + tx * 4]) =
            make_float4(acc[e][0], acc[e][1], acc[e][2], acc[e][3]);
    }
}

// ---------------------------------------------------------------------------
extern "C" void kernel_launch(void* const* d_in, const int* in_sizes, int n_in,
                              void* d_out, int out_size, void* d_ws, size_t ws_size,
                              hipStream_t stream)
{
    const float* m        = (const float*)d_in[0];
    const float* z        = (const float*)d_in[1];
    const float* msa_mask = (const float*)d_in[2];
    const float* z_mask   = (const float*)d_in[3];
    const float* ln_m_g   = (const float*)d_in[4];
    const float* ln_m_b   = (const float*)d_in[5];
    const float* w_v      = (const float*)d_in[6];
    const float* w_g      = (const float*)d_in[7];
    const float* ln_z_g   = (const float*)d_in[8];
    const float* ln_z_b   = (const float*)d_in[9];
    const float* w_b      = (const float*)d_in[10];
    const float* w_o      = (const float*)d_in[11];
    float* out = (float*)d_out;

    const size_t wsoft_bytes = (size_t)NH * R_DIM * R_DIM * 2;       // bf16
    const size_t bias_bytes  = (size_t)NH * R_DIM * R_DIM * 4;       // f32
    const size_t wts_bytes   = 4 * 16384 * 2;                        // wv/wg hi+lo
    // per s-row: Vt bf16 + g f32 + o_pre f32
    const size_t per_sch = (size_t)R_DIM * HC * (2 + 4 + 4);
    int SCH = 256;
    while (SCH > 4 &&
           wsoft_bytes + bias_bytes + wts_bytes + (size_t)SCH * per_sch > ws_size)
        SCH >>= 1;

    char* p = (char*)d_ws;
    u16* w_soft   = (u16*)p; p += wsoft_bytes;
    float* biasws = (float*)p; p += bias_bytes;
    u16* wvT_hi   = (u16*)p; p += 16384 * 2;
    u16* wvT_lo   = (u16*)p; p += 16384 * 2;
    u16* wgT_hi   = (u16*)p; p += 16384 * 2;
    u16* wgT_lo   = (u16*)p; p += 16384 * 2;
    u16* Vt       = (u16*)p; p += (size_t)SCH * 32 * NH * R_DIM * 2;
    float* gbuf   = (float*)p; p += (size_t)SCH * R_DIM * HC * 4;
    float* obuf   = (float*)p;

    kW_prep<<<128, 256, 0, stream>>>(w_v, w_g, wvT_hi, wvT_lo, wgT_hi, wgT_lo);
    kA1_bias<<<R_DIM * R_DIM / 4, 256, 0, stream>>>(
        z, z_mask, ln_z_g, ln_z_b, w_b, biasws);
    kA2_softmax<<<NH * R_DIM / 4, 256, 0, stream>>>(biasws, w_soft);

    for (int s0 = 0; s0 < S_DIM; s0 += SCH) {
        kB_mfma<<<dim3(4, SCH * 3), 256, 0, stream>>>(
            m + (size_t)s0 * R_DIM * CM, msa_mask + (size_t)s0 * R_DIM,
            ln_m_g, ln_m_b, wvT_hi, wvT_lo, wgT_hi, wgT_lo, Vt, gbuf, SCH);
        kC_mfma<<<dim3(SCH / 4, 3, NH), 256, 0, stream>>>(w_soft, Vt, obuf, SCH);
        kD_out<<<dim3(SCH * 3), 256, 0, stream>>>(gbuf, obuf, w_o,
                                                  out + (size_t)s0 * R_DIM * CM, SCH);
    }
}

// Round 8
// 361.778 us; speedup vs baseline: 3.4488x; 1.1885x over previous
//
#include <hip/hip_runtime.h>
#include <math.h>

#define S_DIM 512
#define R_DIM 384
#define CM 64
#define CZ 128
#define NH 8
#define CH 32
#define HC 256

typedef unsigned short u16;
typedef __attribute__((ext_vector_type(8))) __bf16 bf16x8;
typedef __attribute__((ext_vector_type(4))) float f32x4;

static __device__ __forceinline__ u16 f2bf(float f) {
    unsigned int u = __float_as_uint(f);
    unsigned int r = (u + 0x7fffu + ((u >> 16) & 1u)) >> 16;
    return (u16)r;
}
static __device__ __forceinline__ float bf2f(u16 h) {
    return __uint_as_float(((unsigned int)h) << 16);
}
static __device__ __forceinline__ void split2(float f, u16& hi, u16& lo) {
    hi = f2bf(f);
    lo = f2bf(f - bf2f(hi));
}

// ---------------------------------------------------------------------------
// Prep: w_v, w_g -> bf16 hi/lo, K-major: wvT[n][c] = w_v[c][n]  (n<256,c<64)
// ---------------------------------------------------------------------------
__global__ __launch_bounds__(256) void kW_prep(
    const float* __restrict__ wv, const float* __restrict__ wg,
    u16* __restrict__ wvT_hi, u16* __restrict__ wvT_lo,
    u16* __restrict__ wgT_hi, u16* __restrict__ wgT_lo)
{
    const int idx = blockIdx.x * 256 + threadIdx.x;   // 2*16384 total
    const int which = idx >> 14;
    const int r = idx & 16383;
    const int n = r >> 6, c = r & 63;
    if (which == 0) split2(wv[c * HC + n], wvT_hi[r], wvT_lo[r]);
    else            split2(wg[c * HC + n], wgT_hi[r], wgT_lo[r]);
}

// ---------------------------------------------------------------------------
// Kernel A1: bias[h][i][j] = LN(z[i,j,:]) @ w_b[:,h] + INF*(z_mask-1)
// one wave per (i,j) row; fully parallel.
// ---------------------------------------------------------------------------
__global__ __launch_bounds__(256) void kA1_bias(
    const float* __restrict__ z, const float* __restrict__ z_mask,
    const float* __restrict__ ln_z_g, const float* __restrict__ ln_z_b,
    const float* __restrict__ w_b, float* __restrict__ bias_ws)
{
    __shared__ float wb_s[CZ * NH];      // 4 KB
    __shared__ float zn_s[4][CZ];        // 2 KB
    const int tid = threadIdx.x, w = tid >> 6, lane = tid & 63;
    const int ridx = blockIdx.x * 4 + w;          // i*R + j

    #pragma unroll
    for (int q = 0; q < 4; ++q) wb_s[tid * 4 + q] = w_b[tid * 4 + q];

    const float2 zz = *reinterpret_cast<const float2*>(
        z + (size_t)ridx * CZ + lane * 2);
    float s1 = zz.x + zz.y;
    float s2 = zz.x * zz.x + zz.y * zz.y;
    #pragma unroll
    for (int msk = 32; msk >= 1; msk >>= 1) {
        s1 += __shfl_xor(s1, msk);
        s2 += __shfl_xor(s2, msk);
    }
    const float mu   = s1 * (1.0f / CZ);
    const float var  = s2 * (1.0f / CZ) - mu * mu;
    const float rstd = rsqrtf(var + 1e-5f);
    const int c0 = lane * 2;
    zn_s[w][c0]     = (zz.x - mu) * rstd * ln_z_g[c0]     + ln_z_b[c0];
    zn_s[w][c0 + 1] = (zz.y - mu) * rstd * ln_z_g[c0 + 1] + ln_z_b[c0 + 1];
    __syncthreads();

    const int h = lane & 7, seg = lane >> 3;
    float acc = 0.f;
    #pragma unroll
    for (int t = 0; t < 16; ++t) {
        const int c = seg * 16 + t;
        acc += zn_s[w][c] * wb_s[c * NH + h];
    }
    acc += __shfl_xor(acc, 8);
    acc += __shfl_xor(acc, 16);
    acc += __shfl_xor(acc, 32);
    if (seg == 0)
        bias_ws[(size_t)h * R_DIM * R_DIM + ridx] =
            acc + 1e8f * (z_mask[ridx] - 1.0f);
}

// ---------------------------------------------------------------------------
// Kernel A2: w_soft[h][i][j] = softmax_j(bias[h][i][j]) -> bf16
// one wave per (h,i) row.
// ---------------------------------------------------------------------------
__global__ __launch_bounds__(256) void kA2_softmax(
    const float* __restrict__ bias_ws, u16* __restrict__ w_soft)
{
    const int tid = threadIdx.x, w = tid >> 6, lane = tid & 63;
    const int row = blockIdx.x * 4 + w;           // h*R + i
    const float* src = bias_ws + (size_t)row * R_DIM;
    float vals[6];
    float mx = -1e30f;
    #pragma unroll
    for (int u = 0; u < 6; ++u) {
        vals[u] = src[lane + u * 64];
        mx = fmaxf(mx, vals[u]);
    }
    #pragma unroll
    for (int msk = 32; msk >= 1; msk >>= 1) mx = fmaxf(mx, __shfl_xor(mx, msk));
    float sum = 0.f;
    #pragma unroll
    for (int u = 0; u < 6; ++u) { vals[u] = __expf(vals[u] - mx); sum += vals[u]; }
    #pragma unroll
    for (int msk = 32; msk >= 1; msk >>= 1) sum += __shfl_xor(sum, msk);
    const float inv = 1.0f / sum;
    u16* dst = w_soft + (size_t)row * R_DIM;
    #pragma unroll
    for (int u = 0; u < 6; ++u)
        dst[lane + u * 64] = f2bf(vals[u] * inv);
}

// ---------------------------------------------------------------------------
// Kernel B (split-MFMA): LN(m) rows -> hi/lo bf16; GEMM vs split wvT/wgT.
// acc = ah*bh + al*bh + ah*bl  (~f32 accurate)
// panel 0,1: V cols 0-127/128-255 -> masked, Vt[h][n][j] bf16
// panel 2,3: G cols 0-127/128-255 -> sigmoid, gbuf[si][k] bf16
// ---------------------------------------------------------------------------
__global__ __launch_bounds__(256) void kB_mfma(
    const float* __restrict__ m_chunk, const float* __restrict__ mask_chunk,
    const float* __restrict__ ln_g, const float* __restrict__ ln_b,
    const u16* __restrict__ wvT_hi, const u16* __restrict__ wvT_lo,
    const u16* __restrict__ wgT_hi, const u16* __restrict__ wgT_lo,
    u16* __restrict__ Vt, u16* __restrict__ gbuf, int SCH)
{
    __shared__ __align__(16) u16 smem[4 * 128 * 72];   // 73728 B
    u16* a_hi = smem;                  // [128][72]
    u16* a_lo = smem + 128 * 72;
    u16* b_hi = smem + 2 * 128 * 72;
    u16* b_lo = smem + 3 * 128 * 72;
    const int tid   = threadIdx.x;
    const int panel = blockIdx.x;      // 0,1 -> V ; 2,3 -> G
    const int si0   = blockIdx.y * 128;
    const int n0    = (panel & 1) * 128;
    const int lane  = tid & 63;
    const int w     = tid >> 6;
    const int wr    = (w >> 1) * 64, wc = (w & 1) * 64;

    { // A: load 128 m rows, LN (pairs of threads per row), split hi/lo
        const int r = tid >> 1, half = tid & 1;
        const float* src = m_chunk + (size_t)(si0 + r) * CM + half * 32;
        float x[32];
        float s1 = 0.f, s2 = 0.f;
        #pragma unroll
        for (int e = 0; e < 8; ++e) {
            float4 v4 = *reinterpret_cast<const float4*>(src + e * 4);
            x[e*4+0] = v4.x; x[e*4+1] = v4.y; x[e*4+2] = v4.z; x[e*4+3] = v4.w;
            s1 += v4.x + v4.y + v4.z + v4.w;
            s2 += v4.x*v4.x + v4.y*v4.y + v4.z*v4.z + v4.w*v4.w;
        }
        s1 += __shfl_xor(s1, 1);
        s2 += __shfl_xor(s2, 1);
        const float mu   = s1 * (1.f / 64);
        const float var  = s2 * (1.f / 64) - mu * mu;
        const float rstd = rsqrtf(var + 1e-5f);
        #pragma unroll
        for (int e = 0; e < 8; ++e) {
            #pragma unroll
            for (int q = 0; q < 4; ++q) {
                const int c = half * 32 + e * 4 + q;
                const float v = (x[e*4+q] - mu) * rstd * ln_g[c] + ln_b[c];
                split2(v, a_hi[r * 72 + c], a_lo[r * 72 + c]);
            }
        }
    }
    { // B: 128 weight rows (n0..n0+127), K=64 contiguous, hi/lo
        const u16* Wh = (panel < 2 ? wvT_hi : wgT_hi) + (size_t)n0 * 64;
        const u16* Wl = (panel < 2 ? wvT_lo : wgT_lo) + (size_t)n0 * 64;
        #pragma unroll
        for (int e = 0; e < 4; ++e) {
            const int c = e * 256 + tid;          // 0..1023
            const int row = c >> 3, off = (c & 7) * 8;
            *reinterpret_cast<uint4*>(&b_hi[row * 72 + off]) =
                *reinterpret_cast<const uint4*>(Wh + row * 64 + off);
            *reinterpret_cast<uint4*>(&b_lo[row * 72 + off]) =
                *reinterpret_cast<const uint4*>(Wl + row * 64 + off);
        }
    }
    __syncthreads();

    f32x4 acc[4][4] = {};
    #pragma unroll
    for (int ks = 0; ks < 2; ++ks) {
        const int ko = ks * 32 + (lane >> 4) * 8;
        bf16x8 ah[4], al[4], bh[4], bl[4];
        #pragma unroll
        for (int mm = 0; mm < 4; ++mm) {
            const int base = (wr + mm * 16 + (lane & 15)) * 72 + ko;
            ah[mm] = *reinterpret_cast<const bf16x8*>(&a_hi[base]);
            al[mm] = *reinterpret_cast<const bf16x8*>(&a_lo[base]);
        }
        #pragma unroll
        for (int nn = 0; nn < 4; ++nn) {
            const int base = (wc + nn * 16 + (lane & 15)) * 72 + ko;
            bh[nn] = *reinterpret_cast<const bf16x8*>(&b_hi[base]);
            bl[nn] = *reinterpret_cast<const bf16x8*>(&b_lo[base]);
        }
        #pragma unroll
        for (int mm = 0; mm < 4; ++mm)
            #pragma unroll
            for (int nn = 0; nn < 4; ++nn) {
                acc[mm][nn] = __builtin_amdgcn_mfma_f32_16x16x32_bf16(
                    ah[mm], bh[nn], acc[mm][nn], 0, 0, 0);
                acc[mm][nn] = __builtin_amdgcn_mfma_f32_16x16x32_bf16(
                    al[mm], bh[nn], acc[mm][nn], 0, 0, 0);
                acc[mm][nn] = __builtin_amdgcn_mfma_f32_16x16x32_bf16(
                    ah[mm], bl[nn], acc[mm][nn], 0, 0, 0);
            }
    }

    __syncthreads();                   // reuse smem as transpose buffer
    const int r4 = (lane >> 4) * 4, cl = lane & 15;
    if (panel < 2) {
        // V: mask rows, transpose to [n][j-local], bf16
        u16* T = smem;                 // [128 n][136 j]
        #pragma unroll
        for (int mm = 0; mm < 4; ++mm) {
            const int rowb = wr + mm * 16 + r4;
            const float4 mk = *reinterpret_cast<const float4*>(mask_chunk + si0 + rowb);
            #pragma unroll
            for (int nn = 0; nn < 4; ++nn) {
                const int n = wc + nn * 16 + cl;
                ushort4 pk;
                pk.x = f2bf(acc[mm][nn][0] * mk.x);
                pk.y = f2bf(acc[mm][nn][1] * mk.y);
                pk.z = f2bf(acc[mm][nn][2] * mk.z);
                pk.w = f2bf(acc[mm][nn][3] * mk.w);
                *reinterpret_cast<ushort4*>(&T[n * 136 + rowb]) = pk;
            }
        }
        __syncthreads();
        const int sc = si0 / R_DIM, j0 = si0 % R_DIM;
        const size_t Nn = (size_t)SCH * 32;
        #pragma unroll
        for (int e = 0; e < 8; ++e) {
            const int c = e * 256 + tid;          // 0..2047
            const int n = c >> 4, part = c & 15;
            const int k = n0 + n;
            const int h = k >> 5, cc = k & 31;
            u16* dst = Vt + ((size_t)h * Nn + (size_t)sc * 32 + cc) * R_DIM
                         + j0 + part * 8;
            *reinterpret_cast<uint4*>(dst) =
                *reinterpret_cast<const uint4*>(&T[n * 136 + part * 8]);
        }
    } else {
        // G: sigmoid -> bf16, natural [si][k] layout
        u16* T = smem;                 // [128 si][136 k] bf16
        #pragma unroll
        for (int mm = 0; mm < 4; ++mm) {
            const int rowb = wr + mm * 16 + r4;
            #pragma unroll
            for (int nn = 0; nn < 4; ++nn) {
                const int n = wc + nn * 16 + cl;
                #pragma unroll
                for (int r = 0; r < 4; ++r)
                    T[(rowb + r) * 136 + n] =
                        f2bf(1.f / (1.f + __expf(-acc[mm][nn][r])));
            }
        }
        __syncthreads();
        #pragma unroll
        for (int e = 0; e < 8; ++e) {
            const int c = e * 256 + tid;          // 0..2047
            const int row = c >> 4, part = c & 15;
            u16* dst = gbuf + (size_t)(si0 + row) * HC + n0 + part * 8;
            *reinterpret_cast<uint4*>(dst) =
                *reinterpret_cast<const uint4*>(&T[row * 136 + part * 8]);
        }
    }
}

// ---------------------------------------------------------------------------
// Kernel C: per-head MFMA GEMM  o_pre[i,n] = sum_j W_h[i,j] * V_h[j,n]
// writes o_pre bf16 [sc*R + i][h*32+c]
// ---------------------------------------------------------------------------
__global__ __launch_bounds__(256) void kC_mfma(
    const u16* __restrict__ Wsoft, const u16* __restrict__ Vt,
    u16* __restrict__ o_pre, int SCH)
{
    constexpr int LDSP = 40;
    __shared__ __align__(16) u16 lds_a[128 * LDSP];
    __shared__ __align__(16) u16 lds_b[128 * LDSP];
    const int N   = SCH * 32;
    const int n0  = blockIdx.x * 128;
    const int i0  = blockIdx.y * 128;
    const int h   = blockIdx.z;
    const int tid = threadIdx.x;
    const int lane = tid & 63;
    const int w    = tid >> 6;
    const int wr   = (w >> 1) * 64;
    const int wc   = (w & 1) * 64;

    const u16* Wp = Wsoft + (size_t)h * R_DIM * R_DIM;
    const u16* Vp = Vt    + (size_t)h * N * R_DIM;

    f32x4 acc[4][4] = {};

    for (int k0 = 0; k0 < R_DIM; k0 += 32) {
        __syncthreads();
        #pragma unroll
        for (int rep = 0; rep < 2; ++rep) {
            const int c = rep * 256 + tid;
            const int row = c >> 2, q = c & 3;
            uint4 va = *reinterpret_cast<const uint4*>(
                Wp + (size_t)(i0 + row) * R_DIM + k0 + q * 8);
            *reinterpret_cast<uint4*>(&lds_a[row * LDSP + q * 8]) = va;
            uint4 vb = *reinterpret_cast<const uint4*>(
                Vp + (size_t)(n0 + row) * R_DIM + k0 + q * 8);
            *reinterpret_cast<uint4*>(&lds_b[row * LDSP + q * 8]) = vb;
        }
        __syncthreads();

        bf16x8 afrag[4], bfrag[4];
        #pragma unroll
        for (int mm = 0; mm < 4; ++mm) {
            const int row = wr + mm * 16 + (lane & 15);
            afrag[mm] = *reinterpret_cast<const bf16x8*>(
                &lds_a[row * LDSP + (lane >> 4) * 8]);
        }
        #pragma unroll
        for (int nn = 0; nn < 4; ++nn) {
            const int row = wc + nn * 16 + (lane & 15);
            bfrag[nn] = *reinterpret_cast<const bf16x8*>(
                &lds_b[row * LDSP + (lane >> 4) * 8]);
        }
        #pragma unroll
        for (int mm = 0; mm < 4; ++mm)
            #pragma unroll
            for (int nn = 0; nn < 4; ++nn)
                acc[mm][nn] = __builtin_amdgcn_mfma_f32_16x16x32_bf16(
                    afrag[mm], bfrag[nn], acc[mm][nn], 0, 0, 0);
    }

    const int r4 = (lane >> 4) * 4;
    const int cl = lane & 15;
    #pragma unroll
    for (int mm = 0; mm < 4; ++mm) {
        #pragma unroll
        for (int nn = 0; nn < 4; ++nn) {
            const int i = i0 + wr + mm * 16 + r4;
            const int n = n0 + wc + nn * 16 + cl;
            const int sc = n >> 5, cc = n & 31;
            u16* dst = &o_pre[((size_t)sc * R_DIM + i) * HC + h * 32 + cc];
            #pragma unroll
            for (int r = 0; r < 4; ++r)
                dst[(size_t)r * HC] = f2bf(acc[mm][nn][r]);
        }
    }
}

// ---------------------------------------------------------------------------
// Kernel D: out[si, :] = (g[si,:] * o_pre[si,:]) @ w_o  (K=256, N=64)
// fp32 VALU GEMM (proven); A-tile loads bf16 g/o, product in f32.
// ---------------------------------------------------------------------------
__global__ __launch_bounds__(256) void kD_out(
    const u16* __restrict__ gbuf, const u16* __restrict__ o_pre,
    const float* __restrict__ w_o, float* __restrict__ out_chunk, int SCH)
{
    __shared__ float A[128 * 65];
    __shared__ float Bt[64 * 64];
    const int si0 = blockIdx.x * 128;
    const int tid = threadIdx.x;
    const int tx  = tid & 15, ty = tid >> 4;
    float acc[8][4] = {};

    for (int k0 = 0; k0 < HC; k0 += 64) {
        { // A tile = g * o_pre (bf16 loads -> f32 product)
            const int r = tid >> 1, half = tid & 1;
            const size_t base = (size_t)(si0 + r) * HC + k0 + half * 32;
            float* dst = &A[r * 65 + half * 32];
            #pragma unroll
            for (int e = 0; e < 4; ++e) {
                uint4 gv = *reinterpret_cast<const uint4*>(gbuf + base + e * 8);
                uint4 ov = *reinterpret_cast<const uint4*>(o_pre + base + e * 8);
                const u16* ga = (const u16*)&gv;
                const u16* oa = (const u16*)&ov;
                #pragma unroll
                for (int q = 0; q < 8; ++q)
                    dst[e * 8 + q] = bf2f(ga[q]) * bf2f(oa[q]);
            }
        }
        { // w_o tile
            const int kk = tid >> 2, q = tid & 3;
            #pragma unroll
            for (int e = 0; e < 4; ++e) {
                float4 v4 = *reinterpret_cast<const float4*>(
                    w_o + (size_t)(k0 + kk) * CM + q * 16 + e * 4);
                *reinterpret_cast<float4*>(&Bt[kk * 64 + q * 16 + e * 4]) = v4;
            }
        }
        __syncthreads();
        #pragma unroll 8
        for (int kk = 0; kk < 64; ++kk) {
            float4 b = *reinterpret_cast<float4*>(&Bt[kk * 64 + tx * 4]);
            #pragma unroll
            for (int e = 0; e < 8; ++e) {
                float a = A[(ty * 8 + e) * 65 + kk];
                acc[e][0] += a * b.x; acc[e][1] += a * b.y;
                acc[e][2] += a * b.z; acc[e][3] += a * b.w;
            }
        }
        __syncthreads();
    }
    #pragma unroll
    for (int e = 0; e < 8; ++e) {
        *reinterpret_cast<float4*>(
            &out_chunk[(size_t)(si0 + ty * 8 + e) * CM + tx * 4]) =
            make_float4(acc[e][0], acc[e][1], acc[e][2], acc[e][3]);
    }
}

// ---------------------------------------------------------------------------
extern "C" void kernel_launch(void* const* d_in, const int* in_sizes, int n_in,
                              void* d_out, int out_size, void* d_ws, size_t ws_size,
                              hipStream_t stream)
{
    const float* m        = (const float*)d_in[0];
    const float* z        = (const float*)d_in[1];
    const float* msa_mask = (const float*)d_in[2];
    const float* z_mask   = (const float*)d_in[3];
    const float* ln_m_g   = (const float*)d_in[4];
    const float* ln_m_b   = (const float*)d_in[5];
    const float* w_v      = (const float*)d_in[6];
    const float* w_g      = (const float*)d_in[7];
    const float* ln_z_g   = (const float*)d_in[8];
    const float* ln_z_b   = (const float*)d_in[9];
    const float* w_b      = (const float*)d_in[10];
    const float* w_o      = (const float*)d_in[11];
    float* out = (float*)d_out;

    const size_t wsoft_bytes = (size_t)NH * R_DIM * R_DIM * 2;       // bf16
    const size_t bias_bytes  = (size_t)NH * R_DIM * R_DIM * 4;       // f32
    const size_t wts_bytes   = 4 * 16384 * 2;                        // wv/wg hi+lo
    // per s-row: Vt bf16 + g bf16 + o_pre bf16
    const size_t per_sch = (size_t)R_DIM * HC * (2 + 2 + 2);
    int SCH = 256;
    while (SCH > 4 &&
           wsoft_bytes + bias_bytes + wts_bytes + (size_t)SCH * per_sch > ws_size)
        SCH >>= 1;

    char* p = (char*)d_ws;
    u16* w_soft   = (u16*)p; p += wsoft_bytes;
    float* biasws = (float*)p; p += bias_bytes;
    u16* wvT_hi   = (u16*)p; p += 16384 * 2;
    u16* wvT_lo   = (u16*)p; p += 16384 * 2;
    u16* wgT_hi   = (u16*)p; p += 16384 * 2;
    u16* wgT_lo   = (u16*)p; p += 16384 * 2;
    u16* Vt       = (u16*)p; p += (size_t)SCH * 32 * NH * R_DIM * 2;
    u16* gbuf     = (u16*)p; p += (size_t)SCH * R_DIM * HC * 2;
    u16* obuf     = (u16*)p;

    kW_prep<<<128, 256, 0, stream>>>(w_v, w_g, wvT_hi, wvT_lo, wgT_hi, wgT_lo);
    kA1_bias<<<R_DIM * R_DIM / 4, 256, 0, stream>>>(
        z, z_mask, ln_z_g, ln_z_b, w_b, biasws);
    kA2_softmax<<<NH * R_DIM / 4, 256, 0, stream>>>(biasws, w_soft);

    for (int s0 = 0; s0 < S_DIM; s0 += SCH) {
        kB_mfma<<<dim3(4, SCH * 3), 256, 0, stream>>>(
            m + (size_t)s0 * R_DIM * CM, msa_mask + (size_t)s0 * R_DIM,
            ln_m_g, ln_m_b, wvT_hi, wvT_lo, wgT_hi, wgT_lo, Vt, gbuf, SCH);
        kC_mfma<<<dim3(SCH / 4, 3, NH), 256, 0, stream>>>(w_soft, Vt, obuf, SCH);
        kD_out<<<dim3(SCH * 3), 256, 0, stream>>>(gbuf, obuf, w_o,
                                                  out + (size_t)s0 * R_DIM * CM, SCH);
    }
}

// Round 9
// 328.095 us; speedup vs baseline: 3.8029x; 1.1027x over previous
//
#include <hip/hip_runtime.h>
#include <math.h>

#define S_DIM 512
#define R_DIM 384
#define CM 64
#define CZ 128
#define NH 8
#define CH 32
#define HC 256

typedef unsigned short u16;
typedef __attribute__((ext_vector_type(8))) __bf16 bf16x8;
typedef __attribute__((ext_vector_type(4))) float f32x4;

static __device__ __forceinline__ u16 f2bf(float f) {
    unsigned int u = __float_as_uint(f);
    unsigned int r = (u + 0x7fffu + ((u >> 16) & 1u)) >> 16;
    return (u16)r;
}
static __device__ __forceinline__ float bf2f(u16 h) {
    return __uint_as_float(((unsigned int)h) << 16);
}
static __device__ __forceinline__ void split2(float f, u16& hi, u16& lo) {
    hi = f2bf(f);
    lo = f2bf(f - bf2f(hi));
}

// ---------------------------------------------------------------------------
// Prep: w_v, w_g -> bf16 hi/lo K-major (wvT[n][c] = w_v[c][n], n<256,c<64);
//       w_b -> wbT[n][c] = w_b[c][n] (n<16 padded, c<128), hi/lo.
// ---------------------------------------------------------------------------
__global__ __launch_bounds__(256) void kW_prep(
    const float* __restrict__ wv, const float* __restrict__ wg,
    const float* __restrict__ wb,
    u16* __restrict__ wvT_hi, u16* __restrict__ wvT_lo,
    u16* __restrict__ wgT_hi, u16* __restrict__ wgT_lo,
    u16* __restrict__ wbT_hi, u16* __restrict__ wbT_lo)
{
    const int idx = blockIdx.x * 256 + threadIdx.x;
    if (idx < 16384) {
        const int n = idx >> 6, c = idx & 63;
        split2(wv[c * HC + n], wvT_hi[idx], wvT_lo[idx]);
    } else if (idx < 32768) {
        const int r = idx - 16384;
        const int n = r >> 6, c = r & 63;
        split2(wg[c * HC + n], wgT_hi[r], wgT_lo[r]);
    } else if (idx < 34816) {
        const int r = idx - 32768;
        const int n = r >> 7, c = r & 127;
        split2(n < NH ? wb[c * NH + n] : 0.f, wbT_hi[r], wbT_lo[r]);
    }
}

// ---------------------------------------------------------------------------
// Kernel A1 (split-MFMA): bias[h][row] = LN(z[row,:]) @ w_b[:,h] + INF*(mask-1)
// 128 rows/block; LN 2 threads/row (1 shfl); matvec via MFMA (N padded to 16).
// ---------------------------------------------------------------------------
__global__ __launch_bounds__(256) void kA1_bias(
    const float* __restrict__ z, const float* __restrict__ z_mask,
    const float* __restrict__ ln_z_g, const float* __restrict__ ln_z_b,
    const u16* __restrict__ wbT_hi, const u16* __restrict__ wbT_lo,
    float* __restrict__ bias_ws)
{
    __shared__ __align__(16) u16 a_hi[128 * 136];   // 34816 B
    __shared__ __align__(16) u16 a_lo[128 * 136];   // 34816 B
    __shared__ __align__(16) u16 b_hi[16 * 136];    // 4352 B
    __shared__ __align__(16) u16 b_lo[16 * 136];    // 4352 B
    const int tid  = threadIdx.x;
    const int lane = tid & 63, w = tid >> 6;
    const int row0 = blockIdx.x * 128;              // global row = i*R + j

    { // A: LN 128 z-rows, 2 threads/row, split hi/lo into LDS
        const int r = tid >> 1, half = tid & 1;
        const float* src = z + (size_t)(row0 + r) * CZ + half * 64;
        float x[64];
        float s1 = 0.f, s2 = 0.f;
        #pragma unroll
        for (int e = 0; e < 16; ++e) {
            float4 v4 = *reinterpret_cast<const float4*>(src + e * 4);
            x[e*4+0] = v4.x; x[e*4+1] = v4.y; x[e*4+2] = v4.z; x[e*4+3] = v4.w;
            s1 += v4.x + v4.y + v4.z + v4.w;
            s2 += v4.x*v4.x + v4.y*v4.y + v4.z*v4.z + v4.w*v4.w;
        }
        s1 += __shfl_xor(s1, 1);
        s2 += __shfl_xor(s2, 1);
        const float mu   = s1 * (1.f / CZ);
        const float var  = s2 * (1.f / CZ) - mu * mu;
        const float rstd = rsqrtf(var + 1e-5f);
        #pragma unroll
        for (int e = 0; e < 16; ++e) {
            float4 g4 = *reinterpret_cast<const float4*>(ln_z_g + half * 64 + e * 4);
            float4 b4 = *reinterpret_cast<const float4*>(ln_z_b + half * 64 + e * 4);
            const int c = half * 64 + e * 4;
            split2((x[e*4+0] - mu) * rstd * g4.x + b4.x,
                   a_hi[r * 136 + c + 0], a_lo[r * 136 + c + 0]);
            split2((x[e*4+1] - mu) * rstd * g4.y + b4.y,
                   a_hi[r * 136 + c + 1], a_lo[r * 136 + c + 1]);
            split2((x[e*4+2] - mu) * rstd * g4.z + b4.z,
                   a_hi[r * 136 + c + 2], a_lo[r * 136 + c + 2]);
            split2((x[e*4+3] - mu) * rstd * g4.w + b4.w,
                   a_hi[r * 136 + c + 3], a_lo[r * 136 + c + 3]);
        }
    }
    { // B: wbT [16][128] hi/lo -> LDS (256 threads cover 16x16 chunks)
        const int row = tid >> 4, off = (tid & 15) * 8;
        *reinterpret_cast<uint4*>(&b_hi[row * 136 + off]) =
            *reinterpret_cast<const uint4*>(wbT_hi + row * 128 + off);
        *reinterpret_cast<uint4*>(&b_lo[row * 136 + off]) =
            *reinterpret_cast<const uint4*>(wbT_lo + row * 128 + off);
    }
    __syncthreads();

    const int wr = w * 32;
    f32x4 acc[2] = {};
    #pragma unroll
    for (int ks = 0; ks < 4; ++ks) {
        const int ko = ks * 32 + (lane >> 4) * 8;
        bf16x8 bh = *reinterpret_cast<const bf16x8*>(&b_hi[(lane & 15) * 136 + ko]);
        bf16x8 bl = *reinterpret_cast<const bf16x8*>(&b_lo[(lane & 15) * 136 + ko]);
        #pragma unroll
        for (int mm = 0; mm < 2; ++mm) {
            const int base = (wr + mm * 16 + (lane & 15)) * 136 + ko;
            bf16x8 ah = *reinterpret_cast<const bf16x8*>(&a_hi[base]);
            bf16x8 al = *reinterpret_cast<const bf16x8*>(&a_lo[base]);
            acc[mm] = __builtin_amdgcn_mfma_f32_16x16x32_bf16(ah, bh, acc[mm], 0, 0, 0);
            acc[mm] = __builtin_amdgcn_mfma_f32_16x16x32_bf16(al, bh, acc[mm], 0, 0, 0);
            acc[mm] = __builtin_amdgcn_mfma_f32_16x16x32_bf16(ah, bl, acc[mm], 0, 0, 0);
        }
    }

    __syncthreads();
    float* T = reinterpret_cast<float*>(a_hi);      // [8 h][132 rows] f32
    const int cl = lane & 15, r4 = (lane >> 4) * 4;
    #pragma unroll
    for (int mm = 0; mm < 2; ++mm) {
        if (cl < NH) {
            #pragma unroll
            for (int r = 0; r < 4; ++r)
                T[cl * 132 + wr + mm * 16 + r4 + r] = acc[mm][r];
        }
    }
    __syncthreads();
    { // masked, coalesced write: h = tid>>5, 4 rows each
        const int h = tid >> 5, q = (tid & 31) * 4;
        float4 v  = *reinterpret_cast<const float4*>(&T[h * 132 + q]);
        float4 mk = *reinterpret_cast<const float4*>(z_mask + row0 + q);
        v.x += 1e8f * (mk.x - 1.f);
        v.y += 1e8f * (mk.y - 1.f);
        v.z += 1e8f * (mk.z - 1.f);
        v.w += 1e8f * (mk.w - 1.f);
        *reinterpret_cast<float4*>(
            &bias_ws[(size_t)h * R_DIM * R_DIM + row0 + q]) = v;
    }
}

// ---------------------------------------------------------------------------
// Kernel A2: w_soft[h][i][j] = softmax_j(bias[h][i][j]) -> bf16
// one wave per (h,i) row.
// ---------------------------------------------------------------------------
__global__ __launch_bounds__(256) void kA2_softmax(
    const float* __restrict__ bias_ws, u16* __restrict__ w_soft)
{
    const int tid = threadIdx.x, w = tid >> 6, lane = tid & 63;
    const int row = blockIdx.x * 4 + w;           // h*R + i
    const float* src = bias_ws + (size_t)row * R_DIM;
    float vals[6];
    float mx = -1e30f;
    #pragma unroll
    for (int u = 0; u < 6; ++u) {
        vals[u] = src[lane + u * 64];
        mx = fmaxf(mx, vals[u]);
    }
    #pragma unroll
    for (int msk = 32; msk >= 1; msk >>= 1) mx = fmaxf(mx, __shfl_xor(mx, msk));
    float sum = 0.f;
    #pragma unroll
    for (int u = 0; u < 6; ++u) { vals[u] = __expf(vals[u] - mx); sum += vals[u]; }
    #pragma unroll
    for (int msk = 32; msk >= 1; msk >>= 1) sum += __shfl_xor(sum, msk);
    const float inv = 1.0f / sum;
    u16* dst = w_soft + (size_t)row * R_DIM;
    #pragma unroll
    for (int u = 0; u < 6; ++u)
        dst[lane + u * 64] = f2bf(vals[u] * inv);
}

// ---------------------------------------------------------------------------
// Kernel B (split-MFMA): LN(m) rows -> hi/lo bf16; GEMM vs split wvT/wgT.
// panel 0,1: V cols -> masked, Vt[h][n][j] bf16 ; panel 2,3: G -> sigmoid bf16
// ---------------------------------------------------------------------------
__global__ __launch_bounds__(256) void kB_mfma(
    const float* __restrict__ m_chunk, const float* __restrict__ mask_chunk,
    const float* __restrict__ ln_g, const float* __restrict__ ln_b,
    const u16* __restrict__ wvT_hi, const u16* __restrict__ wvT_lo,
    const u16* __restrict__ wgT_hi, const u16* __restrict__ wgT_lo,
    u16* __restrict__ Vt, u16* __restrict__ gbuf, int SCH)
{
    __shared__ __align__(16) u16 smem[4 * 128 * 72];   // 73728 B
    u16* a_hi = smem;                  // [128][72]
    u16* a_lo = smem + 128 * 72;
    u16* b_hi = smem + 2 * 128 * 72;
    u16* b_lo = smem + 3 * 128 * 72;
    const int tid   = threadIdx.x;
    const int panel = blockIdx.x;      // 0,1 -> V ; 2,3 -> G
    const int si0   = blockIdx.y * 128;
    const int n0    = (panel & 1) * 128;
    const int lane  = tid & 63;
    const int w     = tid >> 6;
    const int wr    = (w >> 1) * 64, wc = (w & 1) * 64;

    { // A: load 128 m rows, LN (pairs of threads per row), split hi/lo
        const int r = tid >> 1, half = tid & 1;
        const float* src = m_chunk + (size_t)(si0 + r) * CM + half * 32;
        float x[32];
        float s1 = 0.f, s2 = 0.f;
        #pragma unroll
        for (int e = 0; e < 8; ++e) {
            float4 v4 = *reinterpret_cast<const float4*>(src + e * 4);
            x[e*4+0] = v4.x; x[e*4+1] = v4.y; x[e*4+2] = v4.z; x[e*4+3] = v4.w;
            s1 += v4.x + v4.y + v4.z + v4.w;
            s2 += v4.x*v4.x + v4.y*v4.y + v4.z*v4.z + v4.w*v4.w;
        }
        s1 += __shfl_xor(s1, 1);
        s2 += __shfl_xor(s2, 1);
        const float mu   = s1 * (1.f / 64);
        const float var  = s2 * (1.f / 64) - mu * mu;
        const float rstd = rsqrtf(var + 1e-5f);
        #pragma unroll
        for (int e = 0; e < 8; ++e) {
            #pragma unroll
            for (int q = 0; q < 4; ++q) {
                const int c = half * 32 + e * 4 + q;
                const float v = (x[e*4+q] - mu) * rstd * ln_g[c] + ln_b[c];
                split2(v, a_hi[r * 72 + c], a_lo[r * 72 + c]);
            }
        }
    }
    { // B: 128 weight rows (n0..n0+127), K=64 contiguous, hi/lo
        const u16* Wh = (panel < 2 ? wvT_hi : wgT_hi) + (size_t)n0 * 64;
        const u16* Wl = (panel < 2 ? wvT_lo : wgT_lo) + (size_t)n0 * 64;
        #pragma unroll
        for (int e = 0; e < 4; ++e) {
            const int c = e * 256 + tid;          // 0..1023
            const int row = c >> 3, off = (c & 7) * 8;
            *reinterpret_cast<uint4*>(&b_hi[row * 72 + off]) =
                *reinterpret_cast<const uint4*>(Wh + row * 64 + off);
            *reinterpret_cast<uint4*>(&b_lo[row * 72 + off]) =
                *reinterpret_cast<const uint4*>(Wl + row * 64 + off);
        }
    }
    __syncthreads();

    f32x4 acc[4][4] = {};
    #pragma unroll
    for (int ks = 0; ks < 2; ++ks) {
        const int ko = ks * 32 + (lane >> 4) * 8;
        bf16x8 ah[4], al[4], bh[4], bl[4];
        #pragma unroll
        for (int mm = 0; mm < 4; ++mm) {
            const int base = (wr + mm * 16 + (lane & 15)) * 72 + ko;
            ah[mm] = *reinterpret_cast<const bf16x8*>(&a_hi[base]);
            al[mm] = *reinterpret_cast<const bf16x8*>(&a_lo[base]);
        }
        #pragma unroll
        for (int nn = 0; nn < 4; ++nn) {
            const int base = (wc + nn * 16 + (lane & 15)) * 72 + ko;
            bh[nn] = *reinterpret_cast<const bf16x8*>(&b_hi[base]);
            bl[nn] = *reinterpret_cast<const bf16x8*>(&b_lo[base]);
        }
        #pragma unroll
        for (int mm = 0; mm < 4; ++mm)
            #pragma unroll
            for (int nn = 0; nn < 4; ++nn) {
                acc[mm][nn] = __builtin_amdgcn_mfma_f32_16x16x32_bf16(
                    ah[mm], bh[nn], acc[mm][nn], 0, 0, 0);
                acc[mm][nn] = __builtin_amdgcn_mfma_f32_16x16x32_bf16(
                    al[mm], bh[nn], acc[mm][nn], 0, 0, 0);
                acc[mm][nn] = __builtin_amdgcn_mfma_f32_16x16x32_bf16(
                    ah[mm], bl[nn], acc[mm][nn], 0, 0, 0);
            }
    }

    __syncthreads();                   // reuse smem as transpose buffer
    const int r4 = (lane >> 4) * 4, cl = lane & 15;
    if (panel < 2) {
        // V: mask rows, transpose to [n][j-local], bf16
        u16* T = smem;                 // [128 n][136 j]
        #pragma unroll
        for (int mm = 0; mm < 4; ++mm) {
            const int rowb = wr + mm * 16 + r4;
            const float4 mk = *reinterpret_cast<const float4*>(mask_chunk + si0 + rowb);
            #pragma unroll
            for (int nn = 0; nn < 4; ++nn) {
                const int n = wc + nn * 16 + cl;
                ushort4 pk;
                pk.x = f2bf(acc[mm][nn][0] * mk.x);
                pk.y = f2bf(acc[mm][nn][1] * mk.y);
                pk.z = f2bf(acc[mm][nn][2] * mk.z);
                pk.w = f2bf(acc[mm][nn][3] * mk.w);
                *reinterpret_cast<ushort4*>(&T[n * 136 + rowb]) = pk;
            }
        }
        __syncthreads();
        const int sc = si0 / R_DIM, j0 = si0 % R_DIM;
        const size_t Nn = (size_t)SCH * 32;
        #pragma unroll
        for (int e = 0; e < 8; ++e) {
            const int c = e * 256 + tid;          // 0..2047
            const int n = c >> 4, part = c & 15;
            const int k = n0 + n;
            const int h = k >> 5, cc = k & 31;
            u16* dst = Vt + ((size_t)h * Nn + (size_t)sc * 32 + cc) * R_DIM
                         + j0 + part * 8;
            *reinterpret_cast<uint4*>(dst) =
                *reinterpret_cast<const uint4*>(&T[n * 136 + part * 8]);
        }
    } else {
        // G: sigmoid -> bf16, natural [si][k] layout
        u16* T = smem;                 // [128 si][136 k] bf16
        #pragma unroll
        for (int mm = 0; mm < 4; ++mm) {
            const int rowb = wr + mm * 16 + r4;
            #pragma unroll
            for (int nn = 0; nn < 4; ++nn) {
                const int n = wc + nn * 16 + cl;
                #pragma unroll
                for (int r = 0; r < 4; ++r)
                    T[(rowb + r) * 136 + n] =
                        f2bf(1.f / (1.f + __expf(-acc[mm][nn][r])));
            }
        }
        __syncthreads();
        #pragma unroll
        for (int e = 0; e < 8; ++e) {
            const int c = e * 256 + tid;          // 0..2047
            const int row = c >> 4, part = c & 15;
            u16* dst = gbuf + (size_t)(si0 + row) * HC + n0 + part * 8;
            *reinterpret_cast<uint4*>(dst) =
                *reinterpret_cast<const uint4*>(&T[row * 136 + part * 8]);
        }
    }
}

// ---------------------------------------------------------------------------
// Kernel C: per-head MFMA GEMM  o_pre[i,n] = sum_j W_h[i,j] * V_h[j,n]
// writes o_pre bf16 [sc*R + i][h*32+c]
// ---------------------------------------------------------------------------
__global__ __launch_bounds__(256) void kC_mfma(
    const u16* __restrict__ Wsoft, const u16* __restrict__ Vt,
    u16* __restrict__ o_pre, int SCH)
{
    constexpr int LDSP = 40;
    __shared__ __align__(16) u16 lds_a[128 * LDSP];
    __shared__ __align__(16) u16 lds_b[128 * LDSP];
    const int N   = SCH * 32;
    const int n0  = blockIdx.x * 128;
    const int i0  = blockIdx.y * 128;
    const int h   = blockIdx.z;
    const int tid = threadIdx.x;
    const int lane = tid & 63;
    const int w    = tid >> 6;
    const int wr   = (w >> 1) * 64;
    const int wc   = (w & 1) * 64;

    const u16* Wp = Wsoft + (size_t)h * R_DIM * R_DIM;
    const u16* Vp = Vt    + (size_t)h * N * R_DIM;

    f32x4 acc[4][4] = {};

    for (int k0 = 0; k0 < R_DIM; k0 += 32) {
        __syncthreads();
        #pragma unroll
        for (int rep = 0; rep < 2; ++rep) {
            const int c = rep * 256 + tid;
            const int row = c >> 2, q = c & 3;
            uint4 va = *reinterpret_cast<const uint4*>(
                Wp + (size_t)(i0 + row) * R_DIM + k0 + q * 8);
            *reinterpret_cast<uint4*>(&lds_a[row * LDSP + q * 8]) = va;
            uint4 vb = *reinterpret_cast<const uint4*>(
                Vp + (size_t)(n0 + row) * R_DIM + k0 + q * 8);
            *reinterpret_cast<uint4*>(&lds_b[row * LDSP + q * 8]) = vb;
        }
        __syncthreads();

        bf16x8 afrag[4], bfrag[4];
        #pragma unroll
        for (int mm = 0; mm < 4; ++mm) {
            const int row = wr + mm * 16 + (lane & 15);
            afrag[mm] = *reinterpret_cast<const bf16x8*>(
                &lds_a[row * LDSP + (lane >> 4) * 8]);
        }
        #pragma unroll
        for (int nn = 0; nn < 4; ++nn) {
            const int row = wc + nn * 16 + (lane & 15);
            bfrag[nn] = *reinterpret_cast<const bf16x8*>(
                &lds_b[row * LDSP + (lane >> 4) * 8]);
        }
        #pragma unroll
        for (int mm = 0; mm < 4; ++mm)
            #pragma unroll
            for (int nn = 0; nn < 4; ++nn)
                acc[mm][nn] = __builtin_amdgcn_mfma_f32_16x16x32_bf16(
                    afrag[mm], bfrag[nn], acc[mm][nn], 0, 0, 0);
    }

    const int r4 = (lane >> 4) * 4;
    const int cl = lane & 15;
    #pragma unroll
    for (int mm = 0; mm < 4; ++mm) {
        #pragma unroll
        for (int nn = 0; nn < 4; ++nn) {
            const int i = i0 + wr + mm * 16 + r4;
            const int n = n0 + wc + nn * 16 + cl;
            const int sc = n >> 5, cc = n & 31;
            u16* dst = &o_pre[((size_t)sc * R_DIM + i) * HC + h * 32 + cc];
            #pragma unroll
            for (int r = 0; r < 4; ++r)
                dst[(size_t)r * HC] = f2bf(acc[mm][nn][r]);
        }
    }
}

// ---------------------------------------------------------------------------
// Kernel D: out[si, :] = (g[si,:] * o_pre[si,:]) @ w_o  (K=256, N=64)
// fp32 VALU GEMM (proven); A-tile loads bf16 g/o, product in f32.
// ---------------------------------------------------------------------------
__global__ __launch_bounds__(256) void kD_out(
    const u16* __restrict__ gbuf, const u16* __restrict__ o_pre,
    const float* __restrict__ w_o, float* __restrict__ out_chunk, int SCH)
{
    __shared__ float A[128 * 65];
    __shared__ float Bt[64 * 64];
    const int si0 = blockIdx.x * 128;
    const int tid = threadIdx.x;
    const int tx  = tid & 15, ty = tid >> 4;
    float acc[8][4] = {};

    for (int k0 = 0; k0 < HC; k0 += 64) {
        { // A tile = g * o_pre (bf16 loads -> f32 product)
            const int r = tid >> 1, half = tid & 1;
            const size_t base = (size_t)(si0 + r) * HC + k0 + half * 32;
            float* dst = &A[r * 65 + half * 32];
            #pragma unroll
            for (int e = 0; e < 4; ++e) {
                uint4 gv = *reinterpret_cast<const uint4*>(gbuf + base + e * 8);
                uint4 ov = *reinterpret_cast<const uint4*>(o_pre + base + e * 8);
                const u16* ga = (const u16*)&gv;
                const u16* oa = (const u16*)&ov;
                #pragma unroll
                for (int q = 0; q < 8; ++q)
                    dst[e * 8 + q] = bf2f(ga[q]) * bf2f(oa[q]);
            }
        }
        { // w_o tile
            const int kk = tid >> 2, q = tid & 3;
            #pragma unroll
            for (int e = 0; e < 4; ++e) {
                float4 v4 = *reinterpret_cast<const float4*>(
                    w_o + (size_t)(k0 + kk) * CM + q * 16 + e * 4);
                *reinterpret_cast<float4*>(&Bt[kk * 64 + q * 16 + e * 4]) = v4;
            }
        }
        __syncthreads();
        #pragma unroll 8
        for (int kk = 0; kk < 64; ++kk) {
            float4 b = *reinterpret_cast<float4*>(&Bt[kk * 64 + tx * 4]);
            #pragma unroll
            for (int e = 0; e < 8; ++e) {
                float a = A[(ty * 8 + e) * 65 + kk];
                acc[e][0] += a * b.x; acc[e][1] += a * b.y;
                acc[e][2] += a * b.z; acc[e][3] += a * b.w;
            }
        }
        __syncthreads();
    }
    #pragma unroll
    for (int e = 0; e < 8; ++e) {
        *reinterpret_cast<float4*>(
            &out_chunk[(size_t)(si0 + ty * 8 + e) * CM + tx * 4]) =
            make_float4(acc[e][0], acc[e][1], acc[e][2], acc[e][3]);
    }
}

// ---------------------------------------------------------------------------
extern "C" void kernel_launch(void* const* d_in, const int* in_sizes, int n_in,
                              void* d_out, int out_size, void* d_ws, size_t ws_size,
                              hipStream_t stream)
{
    const float* m        = (const float*)d_in[0];
    const float* z        = (const float*)d_in[1];
    const float* msa_mask = (const float*)d_in[2];
    const float* z_mask   = (const float*)d_in[3];
    const float* ln_m_g   = (const float*)d_in[4];
    const float* ln_m_b   = (const float*)d_in[5];
    const float* w_v      = (const float*)d_in[6];
    const float* w_g      = (const float*)d_in[7];
    const float* ln_z_g   = (const float*)d_in[8];
    const float* ln_z_b   = (const float*)d_in[9];
    const float* w_b      = (const float*)d_in[10];
    const float* w_o      = (const float*)d_in[11];
    float* out = (float*)d_out;

    const size_t wsoft_bytes = (size_t)NH * R_DIM * R_DIM * 2;       // bf16
    const size_t bias_bytes  = (size_t)NH * R_DIM * R_DIM * 4;       // f32
    const size_t wts_bytes   = 4 * 16384 * 2 + 2 * 2048 * 2;         // wv/wg/wb hi+lo
    // per s-row: Vt bf16 + g bf16 + o_pre bf16
    const size_t per_sch = (size_t)R_DIM * HC * (2 + 2 + 2);
    int SCH = 256;
    while (SCH > 4 &&
           wsoft_bytes + bias_bytes + wts_bytes + (size_t)SCH * per_sch > ws_size)
        SCH >>= 1;

    char* p = (char*)d_ws;
    u16* w_soft   = (u16*)p; p += wsoft_bytes;
    float* biasws = (float*)p; p += bias_bytes;
    u16* wvT_hi   = (u16*)p; p += 16384 * 2;
    u16* wvT_lo   = (u16*)p; p += 16384 * 2;
    u16* wgT_hi   = (u16*)p; p += 16384 * 2;
    u16* wgT_lo   = (u16*)p; p += 16384 * 2;
    u16* wbT_hi   = (u16*)p; p += 2048 * 2;
    u16* wbT_lo   = (u16*)p; p += 2048 * 2;
    u16* Vt       = (u16*)p; p += (size_t)SCH * 32 * NH * R_DIM * 2;
    u16* gbuf     = (u16*)p; p += (size_t)SCH * R_DIM * HC * 2;
    u16* obuf     = (u16*)p;

    kW_prep<<<136, 256, 0, stream>>>(w_v, w_g, w_b, wvT_hi, wvT_lo,
                                     wgT_hi, wgT_lo, wbT_hi, wbT_lo);
    kA1_bias<<<R_DIM * R_DIM / 128, 256, 0, stream>>>(
        z, z_mask, ln_z_g, ln_z_b, wbT_hi, wbT_lo, biasws);
    kA2_softmax<<<NH * R_DIM / 4, 256, 0, stream>>>(biasws, w_soft);

    for (int s0 = 0; s0 < S_DIM; s0 += SCH) {
        kB_mfma<<<dim3(4, SCH * 3), 256, 0, stream>>>(
            m + (size_t)s0 * R_DIM * CM, msa_mask + (size_t)s0 * R_DIM,
            ln_m_g, ln_m_b, wvT_hi, wvT_lo, wgT_hi, wgT_lo, Vt, gbuf, SCH);
        kC_mfma<<<dim3(SCH / 4, 3, NH), 256, 0, stream>>>(w_soft, Vt, obuf, SCH);
        kD_out<<<dim3(SCH * 3), 256, 0, stream>>>(gbuf, obuf, w_o,
                                                  out + (size_t)s0 * R_DIM * CM, SCH);
    }
}

// Round 11
// 317.089 us; speedup vs baseline: 3.9349x; 1.0347x over previous
//
#include <hip/hip_runtime.h>
#include <math.h>

#define S_DIM 512
#define R_DIM 384
#define CM 64
#define CZ 128
#define NH 8
#define CH 32
#define HC 256

typedef unsigned short u16;
typedef __attribute__((ext_vector_type(8))) __bf16 bf16x8;
typedef __attribute__((ext_vector_type(4))) float f32x4;

static __device__ __forceinline__ u16 f2bf(float f) {
    unsigned int u = __float_as_uint(f);
    unsigned int r = (u + 0x7fffu + ((u >> 16) & 1u)) >> 16;
    return (u16)r;
}
static __device__ __forceinline__ float bf2f(u16 h) {
    return __uint_as_float(((unsigned int)h) << 16);
}
static __device__ __forceinline__ void split2(float f, u16& hi, u16& lo) {
    hi = f2bf(f);
    lo = f2bf(f - bf2f(hi));
}

// ---------------------------------------------------------------------------
// Prep: w_v, w_g -> bf16 hi/lo K-major (wvT[n][c] = w_v[c][n], n<256,c<64);
//       w_b -> wbT[n][c] = w_b[c][n] (n<16 padded, c<128), hi/lo.
// ---------------------------------------------------------------------------
__global__ __launch_bounds__(256) void kW_prep(
    const float* __restrict__ wv, const float* __restrict__ wg,
    const float* __restrict__ wb,
    u16* __restrict__ wvT_hi, u16* __restrict__ wvT_lo,
    u16* __restrict__ wgT_hi, u16* __restrict__ wgT_lo,
    u16* __restrict__ wbT_hi, u16* __restrict__ wbT_lo)
{
    const int idx = blockIdx.x * 256 + threadIdx.x;
    if (idx < 16384) {
        const int n = idx >> 6, c = idx & 63;
        split2(wv[c * HC + n], wvT_hi[idx], wvT_lo[idx]);
    } else if (idx < 32768) {
        const int r = idx - 16384;
        const int n = r >> 6, c = r & 63;
        split2(wg[c * HC + n], wgT_hi[r], wgT_lo[r]);
    } else if (idx < 34816) {
        const int r = idx - 32768;
        const int n = r >> 7, c = r & 127;
        split2(n < NH ? wb[c * NH + n] : 0.f, wbT_hi[r], wbT_lo[r]);
    }
}

// ---------------------------------------------------------------------------
// Kernel A1 (split-MFMA): bias[h][row] = LN(z[row,:]) @ w_b[:,h] + INF*(mask-1)
// 128 rows/block; LN 2 threads/row (1 shfl); matvec via MFMA (N padded to 16).
// ---------------------------------------------------------------------------
__global__ __launch_bounds__(256) void kA1_bias(
    const float* __restrict__ z, const float* __restrict__ z_mask,
    const float* __restrict__ ln_z_g, const float* __restrict__ ln_z_b,
    const u16* __restrict__ wbT_hi, const u16* __restrict__ wbT_lo,
    float* __restrict__ bias_ws)
{
    __shared__ __align__(16) u16 a_hi[128 * 136];   // 34816 B
    __shared__ __align__(16) u16 a_lo[128 * 136];   // 34816 B
    __shared__ __align__(16) u16 b_hi[16 * 136];    // 4352 B
    __shared__ __align__(16) u16 b_lo[16 * 136];    // 4352 B
    const int tid  = threadIdx.x;
    const int lane = tid & 63, w = tid >> 6;
    const int row0 = blockIdx.x * 128;              // global row = i*R + j

    { // A: LN 128 z-rows, 2 threads/row, split hi/lo into LDS
        const int r = tid >> 1, half = tid & 1;
        const float* src = z + (size_t)(row0 + r) * CZ + half * 64;
        float x[64];
        float s1 = 0.f, s2 = 0.f;
        #pragma unroll
        for (int e = 0; e < 16; ++e) {
            float4 v4 = *reinterpret_cast<const float4*>(src + e * 4);
            x[e*4+0] = v4.x; x[e*4+1] = v4.y; x[e*4+2] = v4.z; x[e*4+3] = v4.w;
            s1 += v4.x + v4.y + v4.z + v4.w;
            s2 += v4.x*v4.x + v4.y*v4.y + v4.z*v4.z + v4.w*v4.w;
        }
        s1 += __shfl_xor(s1, 1);
        s2 += __shfl_xor(s2, 1);
        const float mu   = s1 * (1.f / CZ);
        const float var  = s2 * (1.f / CZ) - mu * mu;
        const float rstd = rsqrtf(var + 1e-5f);
        #pragma unroll
        for (int e = 0; e < 16; ++e) {
            float4 g4 = *reinterpret_cast<const float4*>(ln_z_g + half * 64 + e * 4);
            float4 b4 = *reinterpret_cast<const float4*>(ln_z_b + half * 64 + e * 4);
            const int c = half * 64 + e * 4;
            split2((x[e*4+0] - mu) * rstd * g4.x + b4.x,
                   a_hi[r * 136 + c + 0], a_lo[r * 136 + c + 0]);
            split2((x[e*4+1] - mu) * rstd * g4.y + b4.y,
                   a_hi[r * 136 + c + 1], a_lo[r * 136 + c + 1]);
            split2((x[e*4+2] - mu) * rstd * g4.z + b4.z,
                   a_hi[r * 136 + c + 2], a_lo[r * 136 + c + 2]);
            split2((x[e*4+3] - mu) * rstd * g4.w + b4.w,
                   a_hi[r * 136 + c + 3], a_lo[r * 136 + c + 3]);
        }
    }
    { // B: wbT [16][128] hi/lo -> LDS
        const int row = tid >> 4, off = (tid & 15) * 8;
        *reinterpret_cast<uint4*>(&b_hi[row * 136 + off]) =
            *reinterpret_cast<const uint4*>(wbT_hi + row * 128 + off);
        *reinterpret_cast<uint4*>(&b_lo[row * 136 + off]) =
            *reinterpret_cast<const uint4*>(wbT_lo + row * 128 + off);
    }
    __syncthreads();

    const int wr = w * 32;
    f32x4 acc[2] = {};
    #pragma unroll
    for (int ks = 0; ks < 4; ++ks) {
        const int ko = ks * 32 + (lane >> 4) * 8;
        bf16x8 bh = *reinterpret_cast<const bf16x8*>(&b_hi[(lane & 15) * 136 + ko]);
        bf16x8 bl = *reinterpret_cast<const bf16x8*>(&b_lo[(lane & 15) * 136 + ko]);
        #pragma unroll
        for (int mm = 0; mm < 2; ++mm) {
            const int base = (wr + mm * 16 + (lane & 15)) * 136 + ko;
            bf16x8 ah = *reinterpret_cast<const bf16x8*>(&a_hi[base]);
            bf16x8 al = *reinterpret_cast<const bf16x8*>(&a_lo[base]);
            acc[mm] = __builtin_amdgcn_mfma_f32_16x16x32_bf16(ah, bh, acc[mm], 0, 0, 0);
            acc[mm] = __builtin_amdgcn_mfma_f32_16x16x32_bf16(al, bh, acc[mm], 0, 0, 0);
            acc[mm] = __builtin_amdgcn_mfma_f32_16x16x32_bf16(ah, bl, acc[mm], 0, 0, 0);
        }
    }

    __syncthreads();
    float* T = reinterpret_cast<float*>(a_hi);      // [8 h][132 rows] f32
    const int cl = lane & 15, r4 = (lane >> 4) * 4;
    #pragma unroll
    for (int mm = 0; mm < 2; ++mm) {
        if (cl < NH) {
            #pragma unroll
            for (int r = 0; r < 4; ++r)
                T[cl * 132 + wr + mm * 16 + r4 + r] = acc[mm][r];
        }
    }
    __syncthreads();
    { // masked, coalesced write: h = tid>>5, 4 rows each
        const int h = tid >> 5, q = (tid & 31) * 4;
        float4 v  = *reinterpret_cast<const float4*>(&T[h * 132 + q]);
        float4 mk = *reinterpret_cast<const float4*>(z_mask + row0 + q);
        v.x += 1e8f * (mk.x - 1.f);
        v.y += 1e8f * (mk.y - 1.f);
        v.z += 1e8f * (mk.z - 1.f);
        v.w += 1e8f * (mk.w - 1.f);
        *reinterpret_cast<float4*>(
            &bias_ws[(size_t)h * R_DIM * R_DIM + row0 + q]) = v;
    }
}

// ---------------------------------------------------------------------------
// Kernel A2: w_soft[h][i][j] = softmax_j(bias[h][i][j]) -> bf16
// one wave per (h,i) row.
// ---------------------------------------------------------------------------
__global__ __launch_bounds__(256) void kA2_softmax(
    const float* __restrict__ bias_ws, u16* __restrict__ w_soft)
{
    const int tid = threadIdx.x, w = tid >> 6, lane = tid & 63;
    const int row = blockIdx.x * 4 + w;           // h*R + i
    const float* src = bias_ws + (size_t)row * R_DIM;
    float vals[6];
    float mx = -1e30f;
    #pragma unroll
    for (int u = 0; u < 6; ++u) {
        vals[u] = src[lane + u * 64];
        mx = fmaxf(mx, vals[u]);
    }
    #pragma unroll
    for (int msk = 32; msk >= 1; msk >>= 1) mx = fmaxf(mx, __shfl_xor(mx, msk));
    float sum = 0.f;
    #pragma unroll
    for (int u = 0; u < 6; ++u) { vals[u] = __expf(vals[u] - mx); sum += vals[u]; }
    #pragma unroll
    for (int msk = 32; msk >= 1; msk >>= 1) sum += __shfl_xor(sum, msk);
    const float inv = 1.0f / sum;
    u16* dst = w_soft + (size_t)row * R_DIM;
    #pragma unroll
    for (int u = 0; u < 6; ++u)
        dst[lane + u * 64] = f2bf(vals[u] * inv);
}

// ---------------------------------------------------------------------------
// Kernel B (split-MFMA, merged, race-free): stage+LN+split A ONCE (LDS),
// loop 4 weight tiles {V0,V1,G0,G1}; B fragments loaded DIRECTLY from global
// (weights are L2-resident); Tbuf is a DEDICATED LDS region (no aliasing).
// V tiles -> masked, Vt[h][n][j] bf16 ; G tiles -> sigmoid -> gbuf bf16.
// ---------------------------------------------------------------------------
__global__ __launch_bounds__(256) void kB_mfma(
    const float* __restrict__ m_chunk, const float* __restrict__ mask_chunk,
    const float* __restrict__ ln_g, const float* __restrict__ ln_b,
    const u16* __restrict__ wvT_hi, const u16* __restrict__ wvT_lo,
    const u16* __restrict__ wgT_hi, const u16* __restrict__ wgT_lo,
    u16* __restrict__ Vt, u16* __restrict__ gbuf, int SCH)
{
    __shared__ __align__(16) u16 a_hi[128 * 72];    // 18432 B
    __shared__ __align__(16) u16 a_lo[128 * 72];    // 18432 B
    __shared__ __align__(16) u16 Tbuf[128 * 136];   // 34816 B ; total 71680 B
    const int tid  = threadIdx.x;
    const int si0  = blockIdx.x * 128;
    const int lane = tid & 63;
    const int w    = tid >> 6;
    const int wr   = (w >> 1) * 64, wc = (w & 1) * 64;

    { // A: load 128 m rows, LN (2 threads/row), split hi/lo, vector stores
        const int r = tid >> 1, half = tid & 1;
        const float* src = m_chunk + (size_t)(si0 + r) * CM + half * 32;
        float x[32];
        float s1 = 0.f, s2 = 0.f;
        #pragma unroll
        for (int e = 0; e < 8; ++e) {
            float4 v4 = *reinterpret_cast<const float4*>(src + e * 4);
            x[e*4+0] = v4.x; x[e*4+1] = v4.y; x[e*4+2] = v4.z; x[e*4+3] = v4.w;
            s1 += v4.x + v4.y + v4.z + v4.w;
            s2 += v4.x*v4.x + v4.y*v4.y + v4.z*v4.z + v4.w*v4.w;
        }
        s1 += __shfl_xor(s1, 1);
        s2 += __shfl_xor(s2, 1);
        const float mu   = s1 * (1.f / 64);
        const float var  = s2 * (1.f / 64) - mu * mu;
        const float rstd = rsqrtf(var + 1e-5f);
        u16 ph[32], pl[32];
        #pragma unroll
        for (int e = 0; e < 8; ++e) {
            #pragma unroll
            for (int q = 0; q < 4; ++q) {
                const int cl_ = e * 4 + q;
                const int c = half * 32 + cl_;
                const float v = (x[cl_] - mu) * rstd * ln_g[c] + ln_b[c];
                split2(v, ph[cl_], pl[cl_]);
            }
        }
        u16* dh = &a_hi[r * 72 + half * 32];
        u16* dl = &a_lo[r * 72 + half * 32];
        #pragma unroll
        for (int e = 0; e < 4; ++e) {
            *reinterpret_cast<uint4*>(dh + e * 8) =
                reinterpret_cast<const uint4*>(ph)[e];
            *reinterpret_cast<uint4*>(dl + e * 8) =
                reinterpret_cast<const uint4*>(pl)[e];
        }
    }
    __syncthreads();    // A visible to all waves; never rewritten after this

    #pragma unroll
    for (int t = 0; t < 4; ++t) {
        const int n0   = (t & 1) * 128;
        const bool isV = (t < 2);
        const u16* Wh = (isV ? wvT_hi : wgT_hi) + (size_t)n0 * 64;
        const u16* Wl = (isV ? wvT_lo : wgT_lo) + (size_t)n0 * 64;

        f32x4 acc[4][4] = {};
        #pragma unroll
        for (int ks = 0; ks < 2; ++ks) {
            const int ko = ks * 32 + (lane >> 4) * 8;
            bf16x8 ah[4], al[4], bh[4], bl[4];
            #pragma unroll
            for (int nn = 0; nn < 4; ++nn) {           // B frags direct from L2
                const size_t base = (size_t)(wc + nn * 16 + (lane & 15)) * 64 + ko;
                bh[nn] = *reinterpret_cast<const bf16x8*>(Wh + base);
                bl[nn] = *reinterpret_cast<const bf16x8*>(Wl + base);
            }
            #pragma unroll
            for (int mm = 0; mm < 4; ++mm) {
                const int abase = (wr + mm * 16 + (lane & 15)) * 72 + ko;
                ah[mm] = *reinterpret_cast<const bf16x8*>(&a_hi[abase]);
                al[mm] = *reinterpret_cast<const bf16x8*>(&a_lo[abase]);
            }
            #pragma unroll
            for (int mm = 0; mm < 4; ++mm)
                #pragma unroll
                for (int nn = 0; nn < 4; ++nn) {
                    acc[mm][nn] = __builtin_amdgcn_mfma_f32_16x16x32_bf16(
                        ah[mm], bh[nn], acc[mm][nn], 0, 0, 0);
                    acc[mm][nn] = __builtin_amdgcn_mfma_f32_16x16x32_bf16(
                        al[mm], bh[nn], acc[mm][nn], 0, 0, 0);
                    acc[mm][nn] = __builtin_amdgcn_mfma_f32_16x16x32_bf16(
                        ah[mm], bl[nn], acc[mm][nn], 0, 0, 0);
                }
        }
        __syncthreads();   // prior tile's Tbuf readers are done (no-op at t=0)

        const int r4 = (lane >> 4) * 4, cl = lane & 15;
        if (isV) {
            // V: mask rows, transpose to [n][j-local], bf16
            #pragma unroll
            for (int mm = 0; mm < 4; ++mm) {
                const int rowb = wr + mm * 16 + r4;
                const float4 mk =
                    *reinterpret_cast<const float4*>(mask_chunk + si0 + rowb);
                #pragma unroll
                for (int nn = 0; nn < 4; ++nn) {
                    const int n = wc + nn * 16 + cl;
                    ushort4 pk;
                    pk.x = f2bf(acc[mm][nn][0] * mk.x);
                    pk.y = f2bf(acc[mm][nn][1] * mk.y);
                    pk.z = f2bf(acc[mm][nn][2] * mk.z);
                    pk.w = f2bf(acc[mm][nn][3] * mk.w);
                    *reinterpret_cast<ushort4*>(&Tbuf[n * 136 + rowb]) = pk;
                }
            }
            __syncthreads();
            const int sc = si0 / R_DIM, j0 = si0 % R_DIM;
            const size_t Nn = (size_t)SCH * 32;
            #pragma unroll
            for (int e = 0; e < 8; ++e) {
                const int c = e * 256 + tid;          // 0..2047
                const int n = c >> 4, part = c & 15;
                const int k = n0 + n;
                const int h = k >> 5, cc = k & 31;
                u16* dst = Vt + ((size_t)h * Nn + (size_t)sc * 32 + cc) * R_DIM
                             + j0 + part * 8;
                *reinterpret_cast<uint4*>(dst) =
                    *reinterpret_cast<const uint4*>(&Tbuf[n * 136 + part * 8]);
            }
        } else {
            // G: sigmoid -> bf16, natural [si][k] layout
            #pragma unroll
            for (int mm = 0; mm < 4; ++mm) {
                const int rowb = wr + mm * 16 + r4;
                #pragma unroll
                for (int nn = 0; nn < 4; ++nn) {
                    const int n = wc + nn * 16 + cl;
                    #pragma unroll
                    for (int r = 0; r < 4; ++r)
                        Tbuf[(rowb + r) * 136 + n] =
                            f2bf(1.f / (1.f + __expf(-acc[mm][nn][r])));
                }
            }
            __syncthreads();
            #pragma unroll
            for (int e = 0; e < 8; ++e) {
                const int c = e * 256 + tid;          // 0..2047
                const int row = c >> 4, part = c & 15;
                u16* dst = gbuf + (size_t)(si0 + row) * HC + n0 + part * 8;
                *reinterpret_cast<uint4*>(dst) =
                    *reinterpret_cast<const uint4*>(&Tbuf[row * 136 + part * 8]);
            }
        }
    }
}

// ---------------------------------------------------------------------------
// Kernel C: per-head MFMA GEMM  o_pre[i,n] = sum_j W_h[i,j] * V_h[j,n]
// writes o_pre bf16 [sc*R + i][h*32+c]
// ---------------------------------------------------------------------------
__global__ __launch_bounds__(256) void kC_mfma(
    const u16* __restrict__ Wsoft, const u16* __restrict__ Vt,
    u16* __restrict__ o_pre, int SCH)
{
    constexpr int LDSP = 40;
    __shared__ __align__(16) u16 lds_a[128 * LDSP];
    __shared__ __align__(16) u16 lds_b[128 * LDSP];
    const int N   = SCH * 32;
    const int n0  = blockIdx.x * 128;
    const int i0  = blockIdx.y * 128;
    const int h   = blockIdx.z;
    const int tid = threadIdx.x;
    const int lane = tid & 63;
    const int w    = tid >> 6;
    const int wr   = (w >> 1) * 64;
    const int wc   = (w & 1) * 64;

    const u16* Wp = Wsoft + (size_t)h * R_DIM * R_DIM;
    const u16* Vp = Vt    + (size_t)h * N * R_DIM;

    f32x4 acc[4][4] = {};

    for (int k0 = 0; k0 < R_DIM; k0 += 32) {
        __syncthreads();
        #pragma unroll
        for (int rep = 0; rep < 2; ++rep) {
            const int c = rep * 256 + tid;
            const int row = c >> 2, q = c & 3;
            uint4 va = *reinterpret_cast<const uint4*>(
                Wp + (size_t)(i0 + row) * R_DIM + k0 + q * 8);
            *reinterpret_cast<uint4*>(&lds_a[row * LDSP + q * 8]) = va;
            uint4 vb = *reinterpret_cast<const uint4*>(
                Vp + (size_t)(n0 + row) * R_DIM + k0 + q * 8);
            *reinterpret_cast<uint4*>(&lds_b[row * LDSP + q * 8]) = vb;
        }
        __syncthreads();

        bf16x8 afrag[4], bfrag[4];
        #pragma unroll
        for (int mm = 0; mm < 4; ++mm) {
            const int row = wr + mm * 16 + (lane & 15);
            afrag[mm] = *reinterpret_cast<const bf16x8*>(
                &lds_a[row * LDSP + (lane >> 4) * 8]);
        }
        #pragma unroll
        for (int nn = 0; nn < 4; ++nn) {
            const int row = wc + nn * 16 + (lane & 15);
            bfrag[nn] = *reinterpret_cast<const bf16x8*>(
                &lds_b[row * LDSP + (lane >> 4) * 8]);
        }
        #pragma unroll
        for (int mm = 0; mm < 4; ++mm)
            #pragma unroll
            for (int nn = 0; nn < 4; ++nn)
                acc[mm][nn] = __builtin_amdgcn_mfma_f32_16x16x32_bf16(
                    afrag[mm], bfrag[nn], acc[mm][nn], 0, 0, 0);
    }

    const int r4 = (lane >> 4) * 4;
    const int cl = lane & 15;
    #pragma unroll
    for (int mm = 0; mm < 4; ++mm) {
        #pragma unroll
        for (int nn = 0; nn < 4; ++nn) {
            const int i = i0 + wr + mm * 16 + r4;
            const int n = n0 + wc + nn * 16 + cl;
            const int sc = n >> 5, cc = n & 31;
            u16* dst = &o_pre[((size_t)sc * R_DIM + i) * HC + h * 32 + cc];
            #pragma unroll
            for (int r = 0; r < 4; ++r)
                dst[(size_t)r * HC] = f2bf(acc[mm][nn][r]);
        }
    }
}

// ---------------------------------------------------------------------------
// Kernel D: out[si, :] = (g[si,:] * o_pre[si,:]) @ w_o  (K=256, N=64)
// fp32 VALU GEMM (proven); A-tile loads bf16 g/o, product in f32.
// ---------------------------------------------------------------------------
__global__ __launch_bounds__(256) void kD_out(
    const u16* __restrict__ gbuf, const u16* __restrict__ o_pre,
    const float* __restrict__ w_o, float* __restrict__ out_chunk, int SCH)
{
    __shared__ float A[128 * 65];
    __shared__ float Bt[64 * 64];
    const int si0 = blockIdx.x * 128;
    const int tid = threadIdx.x;
    const int tx  = tid & 15, ty = tid >> 4;
    float acc[8][4] = {};

    for (int k0 = 0; k0 < HC; k0 += 64) {
        { // A tile = g * o_pre (bf16 loads -> f32 product)
            const int r = tid >> 1, half = tid & 1;
            const size_t base = (size_t)(si0 + r) * HC + k0 + half * 32;
            float* dst = &A[r * 65 + half * 32];
            #pragma unroll
            for (int e = 0; e < 4; ++e) {
                uint4 gv = *reinterpret_cast<const uint4*>(gbuf + base + e * 8);
                uint4 ov = *reinterpret_cast<const uint4*>(o_pre + base + e * 8);
                const u16* ga = (const u16*)&gv;
                const u16* oa = (const u16*)&ov;
                #pragma unroll
                for (int q = 0; q < 8; ++q)
                    dst[e * 8 + q] = bf2f(ga[q]) * bf2f(oa[q]);
            }
        }
        { // w_o tile
            const int kk = tid >> 2, q = tid & 3;
            #pragma unroll
            for (int e = 0; e < 4; ++e) {
                float4 v4 = *reinterpret_cast<const float4*>(
                    w_o + (size_t)(k0 + kk) * CM + q * 16 + e * 4);
                *reinterpret_cast<float4*>(&Bt[kk * 64 + q * 16 + e * 4]) = v4;
            }
        }
        __syncthreads();
        #pragma unroll 8
        for (int kk = 0; kk < 64; ++kk) {
            float4 b = *reinterpret_cast<float4*>(&Bt[kk * 64 + tx * 4]);
            #pragma unroll
            for (int e = 0; e < 8; ++e) {
                float a = A[(ty * 8 + e) * 65 + kk];
                acc[e][0] += a * b.x; acc[e][1] += a * b.y;
                acc[e][2] += a * b.z; acc[e][3] += a * b.w;
            }
        }
        __syncthreads();
    }
    #pragma unroll
    for (int e = 0; e < 8; ++e) {
        *reinterpret_cast<float4*>(
            &out_chunk[(size_t)(si0 + ty * 8 + e) * CM + tx * 4]) =
            make_float4(acc[e][0], acc[e][1], acc[e][2], acc[e][3]);
    }
}

// ---------------------------------------------------------------------------
extern "C" void kernel_launch(void* const* d_in, const int* in_sizes, int n_in,
                              void* d_out, int out_size, void* d_ws, size_t ws_size,
                              hipStream_t stream)
{
    const float* m        = (const float*)d_in[0];
    const float* z        = (const float*)d_in[1];
    const float* msa_mask = (const float*)d_in[2];
    const float* z_mask   = (const float*)d_in[3];
    const float* ln_m_g   = (const float*)d_in[4];
    const float* ln_m_b   = (const float*)d_in[5];
    const float* w_v      = (const float*)d_in[6];
    const float* w_g      = (const float*)d_in[7];
    const float* ln_z_g   = (const float*)d_in[8];
    const float* ln_z_b   = (const float*)d_in[9];
    const float* w_b      = (const float*)d_in[10];
    const float* w_o      = (const float*)d_in[11];
    float* out = (float*)d_out;

    const size_t wsoft_bytes = (size_t)NH * R_DIM * R_DIM * 2;       // bf16
    const size_t bias_bytes  = (size_t)NH * R_DIM * R_DIM * 4;       // f32
    const size_t wts_bytes   = 4 * 16384 * 2 + 2 * 2048 * 2;         // wv/wg/wb hi+lo
    // per s-row: Vt bf16 + g bf16 + o_pre bf16
    const size_t per_sch = (size_t)R_DIM * HC * (2 + 2 + 2);
    int SCH = 256;
    while (SCH > 4 &&
           wsoft_bytes + bias_bytes + wts_bytes + (size_t)SCH * per_sch > ws_size)
        SCH >>= 1;

    char* p = (char*)d_ws;
    u16* w_soft   = (u16*)p; p += wsoft_bytes;
    float* biasws = (float*)p; p += bias_bytes;
    u16* wvT_hi   = (u16*)p; p += 16384 * 2;
    u16* wvT_lo   = (u16*)p; p += 16384 * 2;
    u16* wgT_hi   = (u16*)p; p += 16384 * 2;
    u16* wgT_lo   = (u16*)p; p += 16384 * 2;
    u16* wbT_hi   = (u16*)p; p += 2048 * 2;
    u16* wbT_lo   = (u16*)p; p += 2048 * 2;
    u16* Vt       = (u16*)p; p += (size_t)SCH * 32 * NH * R_DIM * 2;
    u16* gbuf     = (u16*)p; p += (size_t)SCH * R_DIM * HC * 2;
    u16* obuf     = (u16*)p;

    kW_prep<<<136, 256, 0, stream>>>(w_v, w_g, w_b, wvT_hi, wvT_lo,
                                     wgT_hi, wgT_lo, wbT_hi, wbT_lo);
    kA1_bias<<<R_DIM * R_DIM / 128, 256, 0, stream>>>(
        z, z_mask, ln_z_g, ln_z_b, wbT_hi, wbT_lo, biasws);
    kA2_softmax<<<NH * R_DIM / 4, 256, 0, stream>>>(biasws, w_soft);

    for (int s0 = 0; s0 < S_DIM; s0 += SCH) {
        kB_mfma<<<dim3(SCH * 3), 256, 0, stream>>>(
            m + (size_t)s0 * R_DIM * CM, msa_mask + (size_t)s0 * R_DIM,
            ln_m_g, ln_m_b, wvT_hi, wvT_lo, wgT_hi, wgT_lo, Vt, gbuf, SCH);
        kC_mfma<<<dim3(SCH / 4, 3, NH), 256, 0, stream>>>(w_soft, Vt, obuf, SCH);
        kD_out<<<dim3(SCH * 3), 256, 0, stream>>>(gbuf, obuf, w_o,
                                                  out + (size_t)s0 * R_DIM * CM, SCH);
    }
}